// Round 1
// baseline (1692.881 us; speedup 1.0000x reference)
//
#include <hip/hip_runtime.h>

typedef __bf16 bf16x8 __attribute__((ext_vector_type(8)));
typedef float floatx4 __attribute__((ext_vector_type(4)));
typedef unsigned short u16;

#define MFMA16(A,Bv,Cv) __builtin_amdgcn_mfma_f32_16x16x32_bf16(A,Bv,Cv,0,0,0)

__device__ __forceinline__ u16 f2bf(float f){
  unsigned u = __float_as_uint(f);
  return (u16)((u + 0x7fffu + ((u >> 16) & 1u)) >> 16);
}

#define LDK 264   // u16 row stride for [pix][k] LDS tiles (K=256 + 8 pad -> 2-way-free banks)
#define LDO 520   // u16 row stride for K=512 tile

// ---------------- weight prep: fold LN gamma into weights, bf16-convert, row sums ----------------
__global__ void k_prep(const float* __restrict__ Wqkv1, const float* __restrict__ g1, const float* __restrict__ b1,
                       const float* __restrict__ Wqkv2, const float* __restrict__ g2, const float* __restrict__ b2,
                       const float* __restrict__ Wout1, const float* __restrict__ Wout2,
                       const float* __restrict__ Wf1, const float* __restrict__ gf, const float* __restrict__ bfv,
                       const float* __restrict__ Wf2, const float* __restrict__ bout1, const float* __restrict__ bout2,
                       float* __restrict__ Wk1g, float* __restrict__ Wk2g,
                       u16* __restrict__ Wv1g, u16* __restrict__ Wv2g, u16* __restrict__ Wo1, u16* __restrict__ Wo2,
                       u16* __restrict__ Wf1g, u16* __restrict__ Wf2b,
                       float* __restrict__ Ak1, float* __restrict__ Bk1, float* __restrict__ Av1, float* __restrict__ Bv1,
                       float* __restrict__ Ak2, float* __restrict__ Bk2, float* __restrict__ Av2, float* __restrict__ Bv2,
                       float* __restrict__ A3, float* __restrict__ B3, float* __restrict__ bsum)
{
  int bid = blockIdx.x, c = threadIdx.x;
  __shared__ float sa[4], sb[4];
  int wv = c >> 6, ln = c & 63;
  auto rowsum2 = [&](float a, float bb, float* pA, float* pB){
    for(int off=32; off; off>>=1){ a += __shfl_down(a,off,64); bb += __shfl_down(bb,off,64); }
    if(ln==0){ sa[wv]=a; sb[wv]=bb; }
    __syncthreads();
    if(c==0){ *pA = sa[0]+sa[1]+sa[2]+sa[3]; *pB = sb[0]+sb[1]+sb[2]+sb[3]; }
  };
  if(bid < 512){
    int r = bid; float w = Wqkv1[(size_t)(1+r)*256 + c];
    if(r < 256){ float wg = w*g1[c]; Wk1g[(size_t)r*256+c] = wg; rowsum2(wg, w*b1[c], &Ak1[r], &Bk1[r]); }
    else { int rv=r-256; float wg=w*g1[c]; Wv1g[(size_t)rv*256+c] = f2bf(wg); rowsum2(wg, w*b1[c], &Av1[rv], &Bv1[rv]); }
  } else if(bid < 1024){
    int r = bid-512; float w = Wqkv2[(size_t)(1+r)*256 + c];
    if(r < 256){ float wg = w*g2[c]; Wk2g[(size_t)r*256+c] = wg; rowsum2(wg, w*b2[c], &Ak2[r], &Bk2[r]); }
    else { int rv=r-256; float wg=w*g2[c]; Wv2g[(size_t)rv*256+c] = f2bf(wg); rowsum2(wg, w*b2[c], &Av2[rv], &Bv2[rv]); }
  } else if(bid < 1280){
    int r = bid-1024; Wo1[(size_t)r*256+c] = f2bf(Wout1[(size_t)r*256+c]);
    if(bid==1024) bsum[c] = bout1[c] + bout2[c];
  } else if(bid < 1536){
    int r = bid-1280; Wo2[(size_t)r*256+c] = f2bf(Wout2[(size_t)r*256+c]);
  } else if(bid < 2048){
    int r = bid-1536; float w = Wf1[(size_t)r*256+c]; float wg = w*gf[c];
    Wf1g[(size_t)r*256+c] = f2bf(wg); rowsum2(wg, w*bfv[c], &A3[r], &B3[r]);
  } else {
    int r = bid-2048;
    Wf2b[(size_t)r*512+c]     = f2bf(Wf2[(size_t)r*512+c]);
    Wf2b[(size_t)r*512+256+c] = f2bf(Wf2[(size_t)r*512+256+c]);
  }
}

// ---------------- pass 1: per-batch sum/sumsq + raw q for both branches ----------------
// Coalesced rewrite: one float4 of consecutive pixels per thread; channel-rows read 1KB/wave.
__global__ void k_stats_q(const float* __restrict__ x,
                          const float* __restrict__ Wqkv1, const float* __restrict__ g1,
                          const float* __restrict__ Wqkv2, const float* __restrict__ g2,
                          float* __restrict__ stats,
                          float* __restrict__ rawq1, float* __restrict__ rawq2)
{
  int bid = blockIdx.x; int b = bid >> 4, chunk = bid & 15;
  int tid = threadIdx.x;
  __shared__ float wq1[256], wq2[256];
  __shared__ float sred[4], ssred[4];
  wq1[tid] = Wqkv1[tid]*g1[tid];   // row 0 of Wqkv = q projection
  wq2[tid] = Wqkv2[tid]*g2[tid];
  __syncthreads();
  int pix0 = chunk*1024 + tid*4;             // 4 consecutive pixels, same p
  int p = pix0 >> 8, n = pix0 & 255;
  const float* xp = x + ((size_t)b << 22) + pix0;
  float s = 0.f, ss = 0.f;
  floatx4 q1 = {0.f,0.f,0.f,0.f}, q2 = {0.f,0.f,0.f,0.f};
  #pragma unroll 4
  for(int c=0;c<256;c++){
    floatx4 v = *(const floatx4*)&xp[(size_t)c << 14];
    s  += v[0]+v[1]+v[2]+v[3];
    ss += v[0]*v[0]+v[1]*v[1]+v[2]*v[2]+v[3]*v[3];
    q1 += wq1[c]*v;
    q2 += wq2[c]*v;
  }
  *(floatx4*)&rawq2[(size_t)(b*64 + p)*256 + n] = q2;      // [b][p][n]
  #pragma unroll
  for(int i=0;i<4;i++) rawq1[((size_t)(b*256 + n + i))*64 + p] = q1[i];  // [b][n][p]
  int wv = tid>>6, ln = tid&63;
  for(int off=32; off; off>>=1){ s += __shfl_down(s,off,64); ss += __shfl_down(ss,off,64); }
  if(ln==0){ sred[wv]=s; ssred[wv]=ss; }
  __syncthreads();
  if(tid==0){
    atomicAdd(&stats[b],    sred[0]+sred[1]+sred[2]+sred[3]);
    atomicAdd(&stats[16+b], ssred[0]+ssred[1]+ssred[2]+ssred[3]);
  }
}

__global__ void k_finalize(const float* __restrict__ stats, float* __restrict__ derived)
{
  int b = threadIdx.x;
  if(b < 16){
    float M = 4194304.f;
    float mean = stats[b]/M;
    float var  = stats[16+b]/M - mean*mean;
    derived[b] = mean;
    derived[16+b] = rsqrtf(var + 1e-5f);
  }
}

// t[b,o] = bias[o] + sum_c W[o,c]*beta[c] - mean_b*rstd_b*sum_c W[o,c]*g[c]
__global__ void k_tvec(const float* __restrict__ derived,
                       const float* __restrict__ bqkv1, const float* __restrict__ bqkv2,
                       const float* __restrict__ Ak1, const float* __restrict__ Bk1,
                       const float* __restrict__ Av1, const float* __restrict__ Bv1,
                       const float* __restrict__ Ak2, const float* __restrict__ Bk2,
                       const float* __restrict__ Av2, const float* __restrict__ Bv2,
                       float* __restrict__ tk1, float* __restrict__ tv1,
                       float* __restrict__ tk2, float* __restrict__ tv2)
{
  int b = blockIdx.x, c = threadIdx.x;
  float mr = derived[b]*derived[16+b];
  tk1[b*256+c] = bqkv1[1+c]   + Bk1[c] - mr*Ak1[c];
  tv1[b*256+c] = bqkv1[257+c] + Bv1[c] - mr*Av1[c];
  tk2[b*256+c] = bqkv2[1+c]   + Bk2[c] - mr*Ak2[c];
  tv2[b*256+c] = bqkv2[257+c] + Bv2[c] - mr*Av2[c];
}

// softmax over N for rows (b,p)
__global__ void k_softmax2(const float* __restrict__ rawq2, const float* __restrict__ derived,
                           float* __restrict__ scores2)
{
  int row = blockIdx.x; int b = row >> 6; int tid = threadIdx.x;
  __shared__ float sm[4], ssum[4];
  int wv = tid>>6, ln = tid&63;
  float v = derived[16+b]*rawq2[(size_t)row*256 + tid];
  float m = v;
  for(int off=32; off; off>>=1) m = fmaxf(m, __shfl_xor(m,off,64));
  if(ln==0) sm[wv]=m;
  __syncthreads();
  m = fmaxf(fmaxf(sm[0],sm[1]),fmaxf(sm[2],sm[3]));
  float e = __expf(v-m);
  float s = e;
  for(int off=32; off; off>>=1) s += __shfl_xor(s,off,64);
  if(ln==0) ssum[wv]=s;
  __syncthreads();
  s = ssum[0]+ssum[1]+ssum[2]+ssum[3];
  scores2[(size_t)row*256 + tid] = e/s;
}

// softmax over P (64) for rows (b,n) -- one wave
__global__ void k_softmax1(const float* __restrict__ rawq1, const float* __restrict__ derived,
                           float* __restrict__ scores1)
{
  int row = blockIdx.x; int b = row >> 8; int tid = threadIdx.x;
  float v = derived[16+b]*rawq1[(size_t)row*64 + tid];
  float m = v;
  for(int off=32; off; off>>=1) m = fmaxf(m, __shfl_xor(m,off,64));
  float e = __expf(v-m);
  float s = e;
  for(int off=32; off; off>>=1) s += __shfl_xor(s,off,64);
  scores1[(size_t)row*64 + tid] = e/s;
}

// pass 3: xs1[b][c][n] = sum_p S1*x ; xs2[b][c][p] = sum_n S2*x
__global__ void k_xs(const float* __restrict__ x,
                     const float* __restrict__ scores1, const float* __restrict__ scores2,
                     float* __restrict__ xs1, float* __restrict__ xs2)
{
  __shared__ float X[64*257];
  __shared__ float part[256];
  int bid = blockIdx.x; int b = bid >> 8, c = bid & 255;
  int tid = threadIdx.x;
  const float* xp = x + ((size_t)b*4194304 + (size_t)c*16384);
  for(int i=tid; i<16384; i+=256){
    int p = i >> 8, n = i & 255;
    X[p*257 + n] = xp[i];
  }
  __syncthreads();
  {
    int n = tid;
    const float* s1 = scores1 + (size_t)(b*256 + n)*64;
    float acc = 0.f;
    #pragma unroll 8
    for(int p=0;p<64;p++) acc += s1[p]*X[p*257+n];
    xs1[(size_t)(b*256 + c)*256 + n] = acc;
  }
  {
    int p = tid & 63, q = tid >> 6;
    const float* s2 = scores2 + (size_t)(b*64 + p)*256;
    float acc = 0.f;
    #pragma unroll 8
    for(int i=0;i<64;i++){ int n = q*64 + i; acc += s2[n]*X[p*257+n]; }
    part[tid] = acc;
    __syncthreads();
    if(q==0)
      xs2[(size_t)(b*256 + c)*64 + p] = part[p] + part[64+p] + part[128+p] + part[192+p];
  }
}

// ctx2[b][p][o] = rstd*(Wk2g@xs2) + tk2  (store pixel-major so pass5 reads float4 over o)
__global__ void k_ctx2(const float* __restrict__ Wk2g, const float* __restrict__ xs2,
                       const float* __restrict__ tk2, const float* __restrict__ derived,
                       float* __restrict__ ctx2)
{
  __shared__ float xv[4][256];
  int bid = blockIdx.x; int b = bid >> 4, pg = (bid & 15) << 2;
  int o = threadIdx.x;
  #pragma unroll
  for(int j=0;j<4;j++) xv[j][o] = xs2[(size_t)(b*256 + o)*64 + pg + j];
  __syncthreads();
  const float* w = Wk2g + (size_t)o*256;
  float a0=0,a1=0,a2=0,a3=0;
  for(int cc=0;cc<256;cc++){
    float wc = w[cc];
    a0 += wc*xv[0][cc]; a1 += wc*xv[1][cc]; a2 += wc*xv[2][cc]; a3 += wc*xv[3][cc];
  }
  float r = derived[16+b], t = tk2[b*256 + o];
  ctx2[(size_t)(b*64 + pg+0)*256 + o] = r*a0 + t;
  ctx2[(size_t)(b*64 + pg+1)*256 + o] = r*a1 + t;
  ctx2[(size_t)(b*64 + pg+2)*256 + o] = r*a2 + t;
  ctx2[(size_t)(b*64 + pg+3)*256 + o] = r*a3 + t;
}

__global__ void k_ctx1(const float* __restrict__ Wk1g, const float* __restrict__ xs1,
                       const float* __restrict__ tk1, const float* __restrict__ derived,
                       float* __restrict__ ctx1)
{
  __shared__ float xv[4][256];
  int bid = blockIdx.x; int b = bid >> 6, ng = (bid & 63) << 2;
  int o = threadIdx.x;
  #pragma unroll
  for(int j=0;j<4;j++) xv[j][o] = xs1[(size_t)(b*256 + o)*256 + ng + j];
  __syncthreads();
  const float* w = Wk1g + (size_t)o*256;
  float a0=0,a1=0,a2=0,a3=0;
  for(int cc=0;cc<256;cc++){
    float wc = w[cc];
    a0 += wc*xv[0][cc]; a1 += wc*xv[1][cc]; a2 += wc*xv[2][cc]; a3 += wc*xv[3][cc];
  }
  float r = derived[16+b], t = tk1[b*256 + o];
  ctx1[(size_t)(b*256 + ng+0)*256 + o] = r*a0 + t;
  ctx1[(size_t)(b*256 + ng+1)*256 + o] = r*a1 + t;
  ctx1[(size_t)(b*256 + ng+2)*256 + o] = r*a2 + t;
  ctx1[(size_t)(b*256 + ng+3)*256 + o] = r*a3 + t;
}

// ---------------- pass 5: both attention branches fused, MFMA bf16 ----------------
// block = (b, p, 64 n's). v-GEMMs on rstd*x, relu*ctx, Wout GEMMs, +residual -> out (=xnew), LN3 stats.
// Additionally emits xb = bf16(xnew) in pixel-major [b][pix][c] layout for the fast FFN pass.
__global__ __launch_bounds__(256,2) void k_attn(
    const float* __restrict__ x,
    const u16* __restrict__ Wv1g, const u16* __restrict__ Wv2g,
    const u16* __restrict__ Wo1, const u16* __restrict__ Wo2,
    const float* __restrict__ tv1, const float* __restrict__ tv2,
    const float* __restrict__ ctx1, const float* __restrict__ ctx2,
    const float* __restrict__ bsum, const float* __restrict__ derived,
    float* __restrict__ out, float* __restrict__ stats,
    u16* __restrict__ xb)
{
  __shared__ u16 Xs[64*LDK];
  __shared__ u16 Os[64*LDK];
  __shared__ float rs[4], rss[4];
  int bid = blockIdx.x;
  int b = bid >> 8, p = (bid >> 2) & 63, n0 = (bid & 3) << 6;
  int tid = threadIdx.x, wv = tid >> 6, lane = tid & 63, lr = lane & 15, lq = lane >> 4;
  float rstd = derived[16+b];

  { // stage X' = bf16(rstd*x) as [pix][k]
    int pix = tid & 63, c0 = (tid >> 6) * 2;
    const float* xp = x + ((size_t)b*4194304 + (size_t)p*256 + n0 + pix);
    for(int cc = c0; cc < 256; cc += 8){
      float v0 = xp[(size_t)cc*16384];
      float v1 = xp[(size_t)(cc+1)*16384];
      unsigned pk = (unsigned)f2bf(rstd*v0) | ((unsigned)f2bf(rstd*v1) << 16);
      *(unsigned*)&Xs[pix*LDK + cc] = pk;
    }
  }
  __syncthreads();

  floatx4 Dv[4][4], Dy[4][4];
  #pragma unroll
  for(int i=0;i<4;i++){
    #pragma unroll
    for(int j=0;j<4;j++) Dy[i][j] = floatx4{0.f,0.f,0.f,0.f};
  }

  auto gemmX = [&](const u16* __restrict__ W){   // Dv = W @ Xs
    #pragma unroll
    for(int i=0;i<4;i++){
      #pragma unroll
      for(int j=0;j<4;j++) Dv[i][j] = floatx4{0.f,0.f,0.f,0.f};
    }
    for(int k0=0;k0<256;k0+=32){
      bf16x8 Bf[4];
      #pragma unroll
      for(int pt=0;pt<4;pt++) Bf[pt] = *(const bf16x8*)&Xs[(pt*16+lr)*LDK + k0 + lq*8];
      #pragma unroll
      for(int ct=0;ct<4;ct++){
        bf16x8 Af = *(const bf16x8*)&W[(size_t)(wv*64+ct*16+lr)*256 + k0 + lq*8];
        #pragma unroll
        for(int pt=0;pt<4;pt++) Dv[ct][pt] = MFMA16(Af, Bf[pt], Dv[ct][pt]);
      }
    }
  };
  auto gemmO = [&](const u16* __restrict__ W){   // Dy += W @ Os
    for(int k0=0;k0<256;k0+=32){
      bf16x8 Bf[4];
      #pragma unroll
      for(int pt=0;pt<4;pt++) Bf[pt] = *(const bf16x8*)&Os[(pt*16+lr)*LDK + k0 + lq*8];
      #pragma unroll
      for(int ct=0;ct<4;ct++){
        bf16x8 Af = *(const bf16x8*)&W[(size_t)(wv*64+ct*16+lr)*256 + k0 + lq*8];
        #pragma unroll
        for(int pt=0;pt<4;pt++) Dy[ct][pt] = MFMA16(Af, Bf[pt], Dy[ct][pt]);
      }
    }
  };

  // ---- branch 2 (no transpose; ctx indexed by (b,c,p)) ----
  gemmX(Wv2g);
  {
    const float* c2row = ctx2 + (size_t)(b*64+p)*256;
    #pragma unroll
    for(int ct=0;ct<4;ct++){
      int cbase = wv*64 + ct*16 + lq*4;
      float4 tvv = *(const float4*)&tv2[b*256 + cbase];
      float4 cx  = *(const float4*)&c2row[cbase];
      float tb[4] = {tvv.x,tvv.y,tvv.z,tvv.w};
      float cb[4] = {cx.x,cx.y,cx.z,cx.w};
      #pragma unroll
      for(int pt=0;pt<4;pt++){
        int pix = pt*16 + lr;
        unsigned lo = (unsigned)f2bf(fmaxf(Dv[ct][pt][0]+tb[0],0.f)*cb[0])
                    | ((unsigned)f2bf(fmaxf(Dv[ct][pt][1]+tb[1],0.f)*cb[1]) << 16);
        unsigned hi = (unsigned)f2bf(fmaxf(Dv[ct][pt][2]+tb[2],0.f)*cb[2])
                    | ((unsigned)f2bf(fmaxf(Dv[ct][pt][3]+tb[3],0.f)*cb[3]) << 16);
        uint2 o4; o4.x=lo; o4.y=hi;
        *(uint2*)&Os[pix*LDK + cbase] = o4;
      }
    }
  }
  __syncthreads();
  gemmO(Wo2);
  __syncthreads();

  // ---- branch 1 (transposed branch; ctx indexed by (b,c,n)) ----
  gemmX(Wv1g);
  {
    #pragma unroll
    for(int ct=0;ct<4;ct++){
      int cbase = wv*64 + ct*16 + lq*4;
      float4 tvv = *(const float4*)&tv1[b*256 + cbase];
      float tb[4] = {tvv.x,tvv.y,tvv.z,tvv.w};
      #pragma unroll
      for(int pt=0;pt<4;pt++){
        int pix = pt*16 + lr;
        int n = n0 + pix;
        float4 cx = *(const float4*)&ctx1[(size_t)(b*256+n)*256 + cbase];
        float cb[4] = {cx.x,cx.y,cx.z,cx.w};
        unsigned lo = (unsigned)f2bf(fmaxf(Dv[ct][pt][0]+tb[0],0.f)*cb[0])
                    | ((unsigned)f2bf(fmaxf(Dv[ct][pt][1]+tb[1],0.f)*cb[1]) << 16);
        unsigned hi = (unsigned)f2bf(fmaxf(Dv[ct][pt][2]+tb[2],0.f)*cb[2])
                    | ((unsigned)f2bf(fmaxf(Dv[ct][pt][3]+tb[3],0.f)*cb[3]) << 16);
        uint2 o4; o4.x=lo; o4.y=hi;
        *(uint2*)&Os[pix*LDK + cbase] = o4;
      }
    }
  }
  __syncthreads();
  gemmO(Wo1);

  // ---- epilogue: xnew = y1 + y2 + bout1+bout2 + x; LN3 stats; emit bf16 pixel-major copy ----
  float s3=0.f, ss3=0.f;
  #pragma unroll
  for(int ct=0;ct<4;ct++){
    int cbase = wv*64 + ct*16 + lq*4;
    float4 bsv = *(const float4*)&bsum[cbase];
    float bb[4] = {bsv.x,bsv.y,bsv.z,bsv.w};
    #pragma unroll
    for(int pt=0;pt<4;pt++){
      int pix = pt*16 + lr;
      size_t base = (size_t)b*4194304 + (size_t)cbase*16384 + (size_t)p*256 + n0 + pix;
      float vv[4];
      #pragma unroll
      for(int r=0;r<4;r++){
        size_t a = base + (size_t)r*16384;
        float v = Dy[ct][pt][r] + bb[r] + x[a];
        out[a] = v;
        vv[r] = v;
        s3 += v; ss3 += v*v;
      }
      if(xb){
        uint2 pk;
        pk.x = (unsigned)f2bf(vv[0]) | ((unsigned)f2bf(vv[1]) << 16);
        pk.y = (unsigned)f2bf(vv[2]) | ((unsigned)f2bf(vv[3]) << 16);
        *(uint2*)&xb[((size_t)(b*16384 + p*256 + n0 + pix) << 8) + cbase] = pk;
      }
    }
  }
  for(int off=32; off; off>>=1){ s3 += __shfl_down(s3,off,64); ss3 += __shfl_down(ss3,off,64); }
  if(lane==0){ rs[wv]=s3; rss[wv]=ss3; }
  __syncthreads();
  if(tid==0){
    atomicAdd(&stats[32+b], rs[0]+rs[1]+rs[2]+rs[3]);
    atomicAdd(&stats[48+b], rss[0]+rss[1]+rss[2]+rss[3]);
  }
}

__global__ void k_finalize3(const float* __restrict__ stats, float* __restrict__ derived,
                            const float* __restrict__ bf1, const float* __restrict__ A3,
                            const float* __restrict__ B3, float* __restrict__ t3)
{
  int tid = threadIdx.x;
  if(tid < 16){
    float M = 4194304.f;
    float mean = stats[32+tid]/M;
    float var  = stats[48+tid]/M - mean*mean;
    derived[32+tid] = mean;
    derived[48+tid] = rsqrtf(var + 1e-5f);
  }
  __syncthreads();
  float a = A3[tid], bb = B3[tid], bias = bf1[tid];
  for(int b=0;b<16;b++){
    float mr = derived[32+b]*derived[48+b];
    t3[b*512 + tid] = bias + bb - mr*a;
  }
}

// ---------------- pass 6 (fast): FFN, B-fragments load directly from pixel-major xb ----------------
// No Xs staging; LDS = Os only (33 KB) -> 4 blocks/CU. rstd3 folded into GEMM-h epilogue.
__global__ __launch_bounds__(256,4) void k_ffn_fast(
    const u16* __restrict__ xb,
    const u16* __restrict__ Wf1g, const u16* __restrict__ Wf2b,
    const float* __restrict__ t3, const float* __restrict__ bf2,
    const float* __restrict__ derived,
    float* __restrict__ out)
{
  __shared__ u16 Os[32*LDO];
  int bid = blockIdx.x;
  int b = bid >> 9, p = (bid >> 3) & 63, n0 = (bid & 7) << 5;
  int tid = threadIdx.x, wv = tid >> 6, lane = tid & 63, lr = lane & 15, lq = lane >> 4;
  float rstd = derived[48+b];

  const u16* xrow = xb + ((size_t)(b*16384 + p*256 + n0) << 8);

  // GEMM-h: Dh[8][2], f = wv*128 + ct*16; B loaded straight from global (bf16x8 = exact fragment)
  floatx4 Dh[8][2];
  #pragma unroll
  for(int i=0;i<8;i++){ Dh[i][0] = floatx4{0.f,0.f,0.f,0.f}; Dh[i][1] = floatx4{0.f,0.f,0.f,0.f}; }
  for(int k0=0;k0<256;k0+=32){
    bf16x8 Bf[2];
    #pragma unroll
    for(int pt=0;pt<2;pt++) Bf[pt] = *(const bf16x8*)&xrow[((size_t)(pt*16+lr) << 8) + k0 + lq*8];
    #pragma unroll
    for(int ct=0;ct<8;ct++){
      bf16x8 Af = *(const bf16x8*)&Wf1g[(size_t)(wv*128+ct*16+lr)*256 + k0 + lq*8];
      Dh[ct][0] = MFMA16(Af, Bf[0], Dh[ct][0]);
      Dh[ct][1] = MFMA16(Af, Bf[1], Dh[ct][1]);
    }
  }
  // h = clip(rstd*Dh + t3, -1, 1) -> Os
  #pragma unroll
  for(int ct=0;ct<8;ct++){
    int fbase = wv*128 + ct*16 + lq*4;
    float4 tt = *(const float4*)&t3[b*512 + fbase];
    float tb[4] = {tt.x,tt.y,tt.z,tt.w};
    #pragma unroll
    for(int pt=0;pt<2;pt++){
      int pix = pt*16 + lr;
      unsigned lo = (unsigned)f2bf(fminf(fmaxf(rstd*Dh[ct][pt][0]+tb[0],-1.f),1.f))
                  | ((unsigned)f2bf(fminf(fmaxf(rstd*Dh[ct][pt][1]+tb[1],-1.f),1.f)) << 16);
      unsigned hi = (unsigned)f2bf(fminf(fmaxf(rstd*Dh[ct][pt][2]+tb[2],-1.f),1.f))
                  | ((unsigned)f2bf(fminf(fmaxf(rstd*Dh[ct][pt][3]+tb[3],-1.f),1.f)) << 16);
      uint2 o4; o4.x=lo; o4.y=hi;
      *(uint2*)&Os[pix*LDO + fbase] = o4;
    }
  }
  __syncthreads();

  // GEMM-y: K=512
  floatx4 Dy[4][2];
  #pragma unroll
  for(int i=0;i<4;i++){ Dy[i][0] = floatx4{0.f,0.f,0.f,0.f}; Dy[i][1] = floatx4{0.f,0.f,0.f,0.f}; }
  for(int k0=0;k0<512;k0+=32){
    bf16x8 Bf[2];
    #pragma unroll
    for(int pt=0;pt<2;pt++) Bf[pt] = *(const bf16x8*)&Os[(pt*16+lr)*LDO + k0 + lq*8];
    #pragma unroll
    for(int ct=0;ct<4;ct++){
      bf16x8 Af = *(const bf16x8*)&Wf2b[(size_t)(wv*64+ct*16+lr)*512 + k0 + lq*8];
      Dy[ct][0] = MFMA16(Af, Bf[0], Dy[ct][0]);
      Dy[ct][1] = MFMA16(Af, Bf[1], Dy[ct][1]);
    }
  }

  // epilogue: out = xnew + y + bf2 (read-before-write, same thread per element)
  #pragma unroll
  for(int ct=0;ct<4;ct++){
    int obase = wv*64 + ct*16 + lq*4;
    float4 bbv = *(const float4*)&bf2[obase];
    float bb[4] = {bbv.x,bbv.y,bbv.z,bbv.w};
    #pragma unroll
    for(int pt=0;pt<2;pt++){
      int pix = pt*16 + lr;
      size_t base = (size_t)b*4194304 + (size_t)obase*16384 + (size_t)p*256 + n0 + pix;
      #pragma unroll
      for(int r=0;r<4;r++){
        size_t a = base + (size_t)r*16384;
        out[a] = out[a] + Dy[ct][pt][r] + bb[r];
      }
    }
  }
}

// ---------------- pass 6 (fallback, if workspace too small for xb): original staging version ----------------
__global__ __launch_bounds__(256,2) void k_ffn(
    const u16* __restrict__ Wf1g, const u16* __restrict__ Wf2b,
    const float* __restrict__ t3, const float* __restrict__ bf2,
    const float* __restrict__ derived,
    float* __restrict__ out)
{
  __shared__ u16 Xs[32*LDK];
  __shared__ u16 Os[32*LDO];
  int bid = blockIdx.x;
  int b = bid >> 9, p = (bid >> 3) & 63, n0 = (bid & 7) << 5;
  int tid = threadIdx.x, wv = tid >> 6, lane = tid & 63, lr = lane & 15, lq = lane >> 4;
  float rstd = derived[48+b];

  { // stage X3' = bf16(rstd3 * xnew)
    int pix = tid & 31, c0 = (tid >> 5) * 2;
    const float* xp = out + ((size_t)b*4194304 + (size_t)p*256 + n0 + pix);
    for(int cc = c0; cc < 256; cc += 16){
      float v0 = xp[(size_t)cc*16384];
      float v1 = xp[(size_t)(cc+1)*16384];
      unsigned pk = (unsigned)f2bf(rstd*v0) | ((unsigned)f2bf(rstd*v1) << 16);
      *(unsigned*)&Xs[pix*LDK + cc] = pk;
    }
  }
  __syncthreads();

  floatx4 Dh[8][2];
  #pragma unroll
  for(int i=0;i<8;i++){ Dh[i][0] = floatx4{0.f,0.f,0.f,0.f}; Dh[i][1] = floatx4{0.f,0.f,0.f,0.f}; }
  for(int k0=0;k0<256;k0+=32){
    bf16x8 Bf[2];
    #pragma unroll
    for(int pt=0;pt<2;pt++) Bf[pt] = *(const bf16x8*)&Xs[(pt*16+lr)*LDK + k0 + lq*8];
    #pragma unroll
    for(int ct=0;ct<8;ct++){
      bf16x8 Af = *(const bf16x8*)&Wf1g[(size_t)(wv*128+ct*16+lr)*256 + k0 + lq*8];
      Dh[ct][0] = MFMA16(Af, Bf[0], Dh[ct][0]);
      Dh[ct][1] = MFMA16(Af, Bf[1], Dh[ct][1]);
    }
  }
  #pragma unroll
  for(int ct=0;ct<8;ct++){
    int fbase = wv*128 + ct*16 + lq*4;
    float4 tt = *(const float4*)&t3[b*512 + fbase];
    float tb[4] = {tt.x,tt.y,tt.z,tt.w};
    #pragma unroll
    for(int pt=0;pt<2;pt++){
      int pix = pt*16 + lr;
      unsigned lo = (unsigned)f2bf(fminf(fmaxf(Dh[ct][pt][0]+tb[0],-1.f),1.f))
                  | ((unsigned)f2bf(fminf(fmaxf(Dh[ct][pt][1]+tb[1],-1.f),1.f)) << 16);
      unsigned hi = (unsigned)f2bf(fminf(fmaxf(Dh[ct][pt][2]+tb[2],-1.f),1.f))
                  | ((unsigned)f2bf(fminf(fmaxf(Dh[ct][pt][3]+tb[3],-1.f),1.f)) << 16);
      uint2 o4; o4.x=lo; o4.y=hi;
      *(uint2*)&Os[pix*LDO + fbase] = o4;
    }
  }
  __syncthreads();

  floatx4 Dy[4][2];
  #pragma unroll
  for(int i=0;i<4;i++){ Dy[i][0] = floatx4{0.f,0.f,0.f,0.f}; Dy[i][1] = floatx4{0.f,0.f,0.f,0.f}; }
  for(int k0=0;k0<512;k0+=32){
    bf16x8 Bf[2];
    #pragma unroll
    for(int pt=0;pt<2;pt++) Bf[pt] = *(const bf16x8*)&Os[(pt*16+lr)*LDO + k0 + lq*8];
    #pragma unroll
    for(int ct=0;ct<4;ct++){
      bf16x8 Af = *(const bf16x8*)&Wf2b[(size_t)(wv*64+ct*16+lr)*512 + k0 + lq*8];
      Dy[ct][0] = MFMA16(Af, Bf[0], Dy[ct][0]);
      Dy[ct][1] = MFMA16(Af, Bf[1], Dy[ct][1]);
    }
  }

  #pragma unroll
  for(int ct=0;ct<4;ct++){
    int obase = wv*64 + ct*16 + lq*4;
    float4 bbv = *(const float4*)&bf2[obase];
    float bb[4] = {bbv.x,bbv.y,bbv.z,bbv.w};
    #pragma unroll
    for(int pt=0;pt<2;pt++){
      int pix = pt*16 + lr;
      size_t base = (size_t)b*4194304 + (size_t)obase*16384 + (size_t)p*256 + n0 + pix;
      #pragma unroll
      for(int r=0;r<4;r++){
        size_t a = base + (size_t)r*16384;
        out[a] = out[a] + Dy[ct][pt][r] + bb[r];
      }
    }
  }
}

// ---------------- launcher ----------------
extern "C" void kernel_launch(void* const* d_in, const int* in_sizes, int n_in,
                              void* d_out, int out_size, void* d_ws, size_t ws_size,
                              hipStream_t stream)
{
  const float* x     = (const float*)d_in[0];
  const float* g1    = (const float*)d_in[1];
  const float* b1    = (const float*)d_in[2];
  const float* Wqkv1 = (const float*)d_in[3];
  const float* bqkv1 = (const float*)d_in[4];
  const float* Wout1 = (const float*)d_in[5];
  const float* bout1 = (const float*)d_in[6];
  const float* g2    = (const float*)d_in[7];
  const float* b2    = (const float*)d_in[8];
  const float* Wqkv2 = (const float*)d_in[9];
  const float* bqkv2 = (const float*)d_in[10];
  const float* Wout2 = (const float*)d_in[11];
  const float* bout2 = (const float*)d_in[12];
  const float* gf    = (const float*)d_in[13];
  const float* bfv   = (const float*)d_in[14];
  const float* Wf1   = (const float*)d_in[15];
  const float* bf1   = (const float*)d_in[16];
  const float* Wf2   = (const float*)d_in[17];
  const float* bf2   = (const float*)d_in[18];
  float* out = (float*)d_out;
  char* ws = (char*)d_ws;

  float* stats   = (float*)(ws + 0);          // 64 f (zeroed)
  float* derived = (float*)(ws + 256);        // 64 f
  float* bsum    = (float*)(ws + 512);        // 256 f
  float* Ak1 = (float*)(ws + 1536);
  float* Bk1 = (float*)(ws + 2560);
  float* Av1 = (float*)(ws + 3584);
  float* Bv1 = (float*)(ws + 4608);
  float* Ak2 = (float*)(ws + 5632);
  float* Bk2 = (float*)(ws + 6656);
  float* Av2 = (float*)(ws + 7680);
  float* Bv2 = (float*)(ws + 8704);
  float* A3  = (float*)(ws + 9728);
  float* B3  = (float*)(ws + 11776);
  float* tk1 = (float*)(ws + 13824);
  float* tv1 = (float*)(ws + 30208);
  float* tk2 = (float*)(ws + 46592);
  float* tv2 = (float*)(ws + 62976);
  float* t3  = (float*)(ws + 79360);
  float* Wk1g = (float*)(ws + 112128);
  float* Wk2g = (float*)(ws + 374272);
  u16* Wv1g = (u16*)(ws + 636416);
  u16* Wv2g = (u16*)(ws + 767488);
  u16* Wo1  = (u16*)(ws + 898560);
  u16* Wo2  = (u16*)(ws + 1029632);
  u16* Wf1g = (u16*)(ws + 1160704);
  u16* Wf2b = (u16*)(ws + 1422848);
  float* rawq1   = (float*)(ws + 1684992);
  float* rawq2   = (float*)(ws + 2733568);
  float* scores1 = (float*)(ws + 3782144);
  float* scores2 = (float*)(ws + 4830720);
  float* xs1  = (float*)(ws + 5879296);
  float* xs2  = (float*)(ws + 10073600);
  float* ctx1 = (float*)(ws + 11122176);
  float* ctx2 = (float*)(ws + 15316480);
  // xb: bf16(xnew) pixel-major [b][pix][c], 16*16384*256*2 = 128 MiB, at 16 MiB offset
  const size_t XB_OFF  = 16777216;
  const size_t XB_SIZE = (size_t)16*16384*256*2;
  bool fast = (ws_size >= XB_OFF + XB_SIZE);
  u16* xb = fast ? (u16*)(ws + XB_OFF) : (u16*)nullptr;

  hipMemsetAsync(stats, 0, 64*sizeof(float), stream);

  k_prep<<<2304, 256, 0, stream>>>(Wqkv1,g1,b1, Wqkv2,g2,b2, Wout1,Wout2, Wf1,gf,bfv, Wf2, bout1,bout2,
                                   Wk1g,Wk2g, Wv1g,Wv2g,Wo1,Wo2,Wf1g,Wf2b,
                                   Ak1,Bk1,Av1,Bv1, Ak2,Bk2,Av2,Bv2, A3,B3, bsum);
  k_stats_q<<<256, 256, 0, stream>>>(x, Wqkv1,g1, Wqkv2,g2, stats, rawq1, rawq2);
  k_finalize<<<1, 64, 0, stream>>>(stats, derived);
  k_tvec<<<16, 256, 0, stream>>>(derived, bqkv1,bqkv2, Ak1,Bk1,Av1,Bv1, Ak2,Bk2,Av2,Bv2,
                                 tk1,tv1,tk2,tv2);
  k_softmax2<<<1024, 256, 0, stream>>>(rawq2, derived, scores2);
  k_softmax1<<<4096, 64, 0, stream>>>(rawq1, derived, scores1);
  k_xs<<<4096, 256, 0, stream>>>(x, scores1, scores2, xs1, xs2);
  k_ctx2<<<256, 256, 0, stream>>>(Wk2g, xs2, tk2, derived, ctx2);
  k_ctx1<<<1024, 256, 0, stream>>>(Wk1g, xs1, tk1, derived, ctx1);
  k_attn<<<4096, 256, 0, stream>>>(x, Wv1g,Wv2g, Wo1,Wo2, tv1,tv2, ctx1,ctx2,
                                   bsum, derived, out, stats, xb);
  k_finalize3<<<1, 512, 0, stream>>>(stats, derived, bf1, A3, B3, t3);
  if(fast)
    k_ffn_fast<<<8192, 256, 0, stream>>>(xb, Wf1g, Wf2b, t3, bf2, derived, out);
  else
    k_ffn<<<8192, 256, 0, stream>>>(Wf1g, Wf2b, t3, bf2, derived, out);
}

// Round 2
// 1652.359 us; speedup vs baseline: 1.0245x; 1.0245x over previous
//
#include <hip/hip_runtime.h>

typedef __bf16 bf16x8 __attribute__((ext_vector_type(8)));
typedef float floatx4 __attribute__((ext_vector_type(4)));
typedef unsigned short u16;

#define MFMA16(A,Bv,Cv) __builtin_amdgcn_mfma_f32_16x16x32_bf16(A,Bv,Cv,0,0,0)

__device__ __forceinline__ u16 f2bf(float f){
  unsigned u = __float_as_uint(f);
  return (u16)((u + 0x7fffu + ((u >> 16) & 1u)) >> 16);
}

#define LDK 264   // u16 row stride for [pix][k] LDS tiles (K=256 + 8 pad -> 2-way-free banks)
#define LDO 520   // u16 row stride for K=512 tile

// ---------------- weight prep: fold LN gamma into weights, bf16-convert, row sums ----------------
__global__ void k_prep(const float* __restrict__ Wqkv1, const float* __restrict__ g1, const float* __restrict__ b1,
                       const float* __restrict__ Wqkv2, const float* __restrict__ g2, const float* __restrict__ b2,
                       const float* __restrict__ Wout1, const float* __restrict__ Wout2,
                       const float* __restrict__ Wf1, const float* __restrict__ gf, const float* __restrict__ bfv,
                       const float* __restrict__ Wf2, const float* __restrict__ bout1, const float* __restrict__ bout2,
                       float* __restrict__ Wk1g, float* __restrict__ Wk2g,
                       u16* __restrict__ Wv1g, u16* __restrict__ Wv2g, u16* __restrict__ Wo1, u16* __restrict__ Wo2,
                       u16* __restrict__ Wf1g, u16* __restrict__ Wf2b,
                       float* __restrict__ Ak1, float* __restrict__ Bk1, float* __restrict__ Av1, float* __restrict__ Bv1,
                       float* __restrict__ Ak2, float* __restrict__ Bk2, float* __restrict__ Av2, float* __restrict__ Bv2,
                       float* __restrict__ A3, float* __restrict__ B3, float* __restrict__ bsum)
{
  int bid = blockIdx.x, c = threadIdx.x;
  __shared__ float sa[4], sb[4];
  int wv = c >> 6, ln = c & 63;
  auto rowsum2 = [&](float a, float bb, float* pA, float* pB){
    for(int off=32; off; off>>=1){ a += __shfl_down(a,off,64); bb += __shfl_down(bb,off,64); }
    if(ln==0){ sa[wv]=a; sb[wv]=bb; }
    __syncthreads();
    if(c==0){ *pA = sa[0]+sa[1]+sa[2]+sa[3]; *pB = sb[0]+sb[1]+sb[2]+sb[3]; }
  };
  if(bid < 512){
    int r = bid; float w = Wqkv1[(size_t)(1+r)*256 + c];
    if(r < 256){ float wg = w*g1[c]; Wk1g[(size_t)r*256+c] = wg; rowsum2(wg, w*b1[c], &Ak1[r], &Bk1[r]); }
    else { int rv=r-256; float wg=w*g1[c]; Wv1g[(size_t)rv*256+c] = f2bf(wg); rowsum2(wg, w*b1[c], &Av1[rv], &Bv1[rv]); }
  } else if(bid < 1024){
    int r = bid-512; float w = Wqkv2[(size_t)(1+r)*256 + c];
    if(r < 256){ float wg = w*g2[c]; Wk2g[(size_t)r*256+c] = wg; rowsum2(wg, w*b2[c], &Ak2[r], &Bk2[r]); }
    else { int rv=r-256; float wg=w*g2[c]; Wv2g[(size_t)rv*256+c] = f2bf(wg); rowsum2(wg, w*b2[c], &Av2[rv], &Bv2[rv]); }
  } else if(bid < 1280){
    int r = bid-1024; Wo1[(size_t)r*256+c] = f2bf(Wout1[(size_t)r*256+c]);
    if(bid==1024) bsum[c] = bout1[c] + bout2[c];
  } else if(bid < 1536){
    int r = bid-1280; Wo2[(size_t)r*256+c] = f2bf(Wout2[(size_t)r*256+c]);
  } else if(bid < 2048){
    int r = bid-1536; float w = Wf1[(size_t)r*256+c]; float wg = w*gf[c];
    Wf1g[(size_t)r*256+c] = f2bf(wg); rowsum2(wg, w*bfv[c], &A3[r], &B3[r]);
  } else {
    int r = bid-2048;
    Wf2b[(size_t)r*512+c]     = f2bf(Wf2[(size_t)r*512+c]);
    Wf2b[(size_t)r*512+256+c] = f2bf(Wf2[(size_t)r*512+256+c]);
  }
}

// ---------------- pass 1: per-batch sum/sumsq + raw q for both branches ----------------
__global__ void k_stats_q(const float* __restrict__ x,
                          const float* __restrict__ Wqkv1, const float* __restrict__ g1,
                          const float* __restrict__ Wqkv2, const float* __restrict__ g2,
                          float* __restrict__ stats,
                          float* __restrict__ rawq1, float* __restrict__ rawq2)
{
  int bid = blockIdx.x; int b = bid >> 4, chunk = bid & 15;
  int tid = threadIdx.x;
  __shared__ float wq1[256], wq2[256];
  __shared__ float sred[4], ssred[4];
  wq1[tid] = Wqkv1[tid]*g1[tid];   // row 0 of Wqkv = q projection
  wq2[tid] = Wqkv2[tid]*g2[tid];
  __syncthreads();
  int pix0 = chunk*1024 + tid*4;             // 4 consecutive pixels, same p
  int p = pix0 >> 8, n = pix0 & 255;
  const float* xp = x + ((size_t)b << 22) + pix0;
  float s = 0.f, ss = 0.f;
  floatx4 q1 = {0.f,0.f,0.f,0.f}, q2 = {0.f,0.f,0.f,0.f};
  #pragma unroll 4
  for(int c=0;c<256;c++){
    floatx4 v = *(const floatx4*)&xp[(size_t)c << 14];
    s  += v[0]+v[1]+v[2]+v[3];
    ss += v[0]*v[0]+v[1]*v[1]+v[2]*v[2]+v[3]*v[3];
    q1 += wq1[c]*v;
    q2 += wq2[c]*v;
  }
  *(floatx4*)&rawq2[(size_t)(b*64 + p)*256 + n] = q2;      // [b][p][n]
  #pragma unroll
  for(int i=0;i<4;i++) rawq1[((size_t)(b*256 + n + i))*64 + p] = q1[i];  // [b][n][p]
  int wv = tid>>6, ln = tid&63;
  for(int off=32; off; off>>=1){ s += __shfl_down(s,off,64); ss += __shfl_down(ss,off,64); }
  if(ln==0){ sred[wv]=s; ssred[wv]=ss; }
  __syncthreads();
  if(tid==0){
    atomicAdd(&stats[b],    sred[0]+sred[1]+sred[2]+sred[3]);
    atomicAdd(&stats[16+b], ssred[0]+ssred[1]+ssred[2]+ssred[3]);
  }
}

__global__ void k_finalize(const float* __restrict__ stats, float* __restrict__ derived)
{
  int b = threadIdx.x;
  if(b < 16){
    float M = 4194304.f;
    float mean = stats[b]/M;
    float var  = stats[16+b]/M - mean*mean;
    derived[b] = mean;
    derived[16+b] = rsqrtf(var + 1e-5f);
  }
}

// t[b,o] = bias[o] + sum_c W[o,c]*beta[c] - mean_b*rstd_b*sum_c W[o,c]*g[c]
__global__ void k_tvec(const float* __restrict__ derived,
                       const float* __restrict__ bqkv1, const float* __restrict__ bqkv2,
                       const float* __restrict__ Ak1, const float* __restrict__ Bk1,
                       const float* __restrict__ Av1, const float* __restrict__ Bv1,
                       const float* __restrict__ Ak2, const float* __restrict__ Bk2,
                       const float* __restrict__ Av2, const float* __restrict__ Bv2,
                       float* __restrict__ tk1, float* __restrict__ tv1,
                       float* __restrict__ tk2, float* __restrict__ tv2)
{
  int b = blockIdx.x, c = threadIdx.x;
  float mr = derived[b]*derived[16+b];
  tk1[b*256+c] = bqkv1[1+c]   + Bk1[c] - mr*Ak1[c];
  tv1[b*256+c] = bqkv1[257+c] + Bv1[c] - mr*Av1[c];
  tk2[b*256+c] = bqkv2[1+c]   + Bk2[c] - mr*Ak2[c];
  tv2[b*256+c] = bqkv2[257+c] + Bv2[c] - mr*Av2[c];
}

// softmax over N for rows (b,p)
__global__ void k_softmax2(const float* __restrict__ rawq2, const float* __restrict__ derived,
                           float* __restrict__ scores2)
{
  int row = blockIdx.x; int b = row >> 6; int tid = threadIdx.x;
  __shared__ float sm[4], ssum[4];
  int wv = tid>>6, ln = tid&63;
  float v = derived[16+b]*rawq2[(size_t)row*256 + tid];
  float m = v;
  for(int off=32; off; off>>=1) m = fmaxf(m, __shfl_xor(m,off,64));
  if(ln==0) sm[wv]=m;
  __syncthreads();
  m = fmaxf(fmaxf(sm[0],sm[1]),fmaxf(sm[2],sm[3]));
  float e = __expf(v-m);
  float s = e;
  for(int off=32; off; off>>=1) s += __shfl_xor(s,off,64);
  if(ln==0) ssum[wv]=s;
  __syncthreads();
  s = ssum[0]+ssum[1]+ssum[2]+ssum[3];
  scores2[(size_t)row*256 + tid] = e/s;
}

// softmax over P (64) for rows (b,n) -- one wave
__global__ void k_softmax1(const float* __restrict__ rawq1, const float* __restrict__ derived,
                           float* __restrict__ scores1)
{
  int row = blockIdx.x; int b = row >> 8; int tid = threadIdx.x;
  float v = derived[16+b]*rawq1[(size_t)row*64 + tid];
  float m = v;
  for(int off=32; off; off>>=1) m = fmaxf(m, __shfl_xor(m,off,64));
  float e = __expf(v-m);
  float s = e;
  for(int off=32; off; off>>=1) s += __shfl_xor(s,off,64);
  scores1[(size_t)row*64 + tid] = e/s;
}

// pass 3: xs1[b][c][n] = sum_p S1*x ; xs2[b][c][p] = sum_n S2*x
__global__ void k_xs(const float* __restrict__ x,
                     const float* __restrict__ scores1, const float* __restrict__ scores2,
                     float* __restrict__ xs1, float* __restrict__ xs2)
{
  __shared__ float X[64*257];
  __shared__ float part[256];
  int bid = blockIdx.x; int b = bid >> 8, c = bid & 255;
  int tid = threadIdx.x;
  const float* xp = x + ((size_t)b*4194304 + (size_t)c*16384);
  for(int i=tid; i<16384; i+=256){
    int p = i >> 8, n = i & 255;
    X[p*257 + n] = xp[i];
  }
  __syncthreads();
  {
    int n = tid;
    const float* s1 = scores1 + (size_t)(b*256 + n)*64;
    float acc = 0.f;
    #pragma unroll 8
    for(int p=0;p<64;p++) acc += s1[p]*X[p*257+n];
    xs1[(size_t)(b*256 + c)*256 + n] = acc;
  }
  {
    int p = tid & 63, q = tid >> 6;
    const float* s2 = scores2 + (size_t)(b*64 + p)*256;
    float acc = 0.f;
    #pragma unroll 8
    for(int i=0;i<64;i++){ int n = q*64 + i; acc += s2[n]*X[p*257+n]; }
    part[tid] = acc;
    __syncthreads();
    if(q==0)
      xs2[(size_t)(b*256 + c)*64 + p] = part[p] + part[64+p] + part[128+p] + part[192+p];
  }
}

// ctx2[b][p][o] = rstd*(Wk2g@xs2) + tk2  (store pixel-major so pass5 reads float4 over o)
__global__ void k_ctx2(const float* __restrict__ Wk2g, const float* __restrict__ xs2,
                       const float* __restrict__ tk2, const float* __restrict__ derived,
                       float* __restrict__ ctx2)
{
  __shared__ float xv[4][256];
  int bid = blockIdx.x; int b = bid >> 4, pg = (bid & 15) << 2;
  int o = threadIdx.x;
  #pragma unroll
  for(int j=0;j<4;j++) xv[j][o] = xs2[(size_t)(b*256 + o)*64 + pg + j];
  __syncthreads();
  const float* w = Wk2g + (size_t)o*256;
  float a0=0,a1=0,a2=0,a3=0;
  for(int cc=0;cc<256;cc++){
    float wc = w[cc];
    a0 += wc*xv[0][cc]; a1 += wc*xv[1][cc]; a2 += wc*xv[2][cc]; a3 += wc*xv[3][cc];
  }
  float r = derived[16+b], t = tk2[b*256 + o];
  ctx2[(size_t)(b*64 + pg+0)*256 + o] = r*a0 + t;
  ctx2[(size_t)(b*64 + pg+1)*256 + o] = r*a1 + t;
  ctx2[(size_t)(b*64 + pg+2)*256 + o] = r*a2 + t;
  ctx2[(size_t)(b*64 + pg+3)*256 + o] = r*a3 + t;
}

__global__ void k_ctx1(const float* __restrict__ Wk1g, const float* __restrict__ xs1,
                       const float* __restrict__ tk1, const float* __restrict__ derived,
                       float* __restrict__ ctx1)
{
  __shared__ float xv[4][256];
  int bid = blockIdx.x; int b = bid >> 6, ng = (bid & 63) << 2;
  int o = threadIdx.x;
  #pragma unroll
  for(int j=0;j<4;j++) xv[j][o] = xs1[(size_t)(b*256 + o)*256 + ng + j];
  __syncthreads();
  const float* w = Wk1g + (size_t)o*256;
  float a0=0,a1=0,a2=0,a3=0;
  for(int cc=0;cc<256;cc++){
    float wc = w[cc];
    a0 += wc*xv[0][cc]; a1 += wc*xv[1][cc]; a2 += wc*xv[2][cc]; a3 += wc*xv[3][cc];
  }
  float r = derived[16+b], t = tk1[b*256 + o];
  ctx1[(size_t)(b*256 + ng+0)*256 + o] = r*a0 + t;
  ctx1[(size_t)(b*256 + ng+1)*256 + o] = r*a1 + t;
  ctx1[(size_t)(b*256 + ng+2)*256 + o] = r*a2 + t;
  ctx1[(size_t)(b*256 + ng+3)*256 + o] = r*a3 + t;
}

// ---------------- pass 5: both attention branches fused, MFMA bf16 ----------------
// block = (b, p, 64 n's). v-GEMMs on rstd*x, relu*ctx, Wout GEMMs, +residual -> out (=xnew), LN3 stats.
// Emits xb = bf16(xnew) in MFMA-fragment-blob order:
//   blob g = global_pixel/16 (16 pixels); within blob: [chunk=c/32][lane=( (c%32)/8 )*16 + pix%16][8 ch * 2B]
//   -> a wave's B-fragment (ds/global read) at k0 is the contiguous 1KB at g*8192 + (k0/32)*1024 + lane*16.
__global__ __launch_bounds__(256,2) void k_attn(
    const float* __restrict__ x,
    const u16* __restrict__ Wv1g, const u16* __restrict__ Wv2g,
    const u16* __restrict__ Wo1, const u16* __restrict__ Wo2,
    const float* __restrict__ tv1, const float* __restrict__ tv2,
    const float* __restrict__ ctx1, const float* __restrict__ ctx2,
    const float* __restrict__ bsum, const float* __restrict__ derived,
    float* __restrict__ out, float* __restrict__ stats,
    u16* __restrict__ xb)
{
  __shared__ u16 Xs[64*LDK];
  __shared__ u16 Os[64*LDK];
  __shared__ float rs[4], rss[4];
  int bid = blockIdx.x;
  int b = bid >> 8, p = (bid >> 2) & 63, n0 = (bid & 3) << 6;
  int tid = threadIdx.x, wv = tid >> 6, lane = tid & 63, lr = lane & 15, lq = lane >> 4;
  float rstd = derived[16+b];

  { // stage X' = bf16(rstd*x) as [pix][k]
    int pix = tid & 63, c0 = (tid >> 6) * 2;
    const float* xp = x + ((size_t)b*4194304 + (size_t)p*256 + n0 + pix);
    for(int cc = c0; cc < 256; cc += 8){
      float v0 = xp[(size_t)cc*16384];
      float v1 = xp[(size_t)(cc+1)*16384];
      unsigned pk = (unsigned)f2bf(rstd*v0) | ((unsigned)f2bf(rstd*v1) << 16);
      *(unsigned*)&Xs[pix*LDK + cc] = pk;
    }
  }
  __syncthreads();

  floatx4 Dv[4][4], Dy[4][4];
  #pragma unroll
  for(int i=0;i<4;i++){
    #pragma unroll
    for(int j=0;j<4;j++) Dy[i][j] = floatx4{0.f,0.f,0.f,0.f};
  }

  auto gemmX = [&](const u16* __restrict__ W){   // Dv = W @ Xs
    #pragma unroll
    for(int i=0;i<4;i++){
      #pragma unroll
      for(int j=0;j<4;j++) Dv[i][j] = floatx4{0.f,0.f,0.f,0.f};
    }
    for(int k0=0;k0<256;k0+=32){
      bf16x8 Bf[4];
      #pragma unroll
      for(int pt=0;pt<4;pt++) Bf[pt] = *(const bf16x8*)&Xs[(pt*16+lr)*LDK + k0 + lq*8];
      #pragma unroll
      for(int ct=0;ct<4;ct++){
        bf16x8 Af = *(const bf16x8*)&W[(size_t)(wv*64+ct*16+lr)*256 + k0 + lq*8];
        #pragma unroll
        for(int pt=0;pt<4;pt++) Dv[ct][pt] = MFMA16(Af, Bf[pt], Dv[ct][pt]);
      }
    }
  };
  auto gemmO = [&](const u16* __restrict__ W){   // Dy += W @ Os
    for(int k0=0;k0<256;k0+=32){
      bf16x8 Bf[4];
      #pragma unroll
      for(int pt=0;pt<4;pt++) Bf[pt] = *(const bf16x8*)&Os[(pt*16+lr)*LDK + k0 + lq*8];
      #pragma unroll
      for(int ct=0;ct<4;ct++){
        bf16x8 Af = *(const bf16x8*)&W[(size_t)(wv*64+ct*16+lr)*256 + k0 + lq*8];
        #pragma unroll
        for(int pt=0;pt<4;pt++) Dy[ct][pt] = MFMA16(Af, Bf[pt], Dy[ct][pt]);
      }
    }
  };

  // ---- branch 2 (no transpose; ctx indexed by (b,c,p)) ----
  gemmX(Wv2g);
  {
    const float* c2row = ctx2 + (size_t)(b*64+p)*256;
    #pragma unroll
    for(int ct=0;ct<4;ct++){
      int cbase = wv*64 + ct*16 + lq*4;
      float4 tvv = *(const float4*)&tv2[b*256 + cbase];
      float4 cx  = *(const float4*)&c2row[cbase];
      float tb[4] = {tvv.x,tvv.y,tvv.z,tvv.w};
      float cb[4] = {cx.x,cx.y,cx.z,cx.w};
      #pragma unroll
      for(int pt=0;pt<4;pt++){
        int pix = pt*16 + lr;
        unsigned lo = (unsigned)f2bf(fmaxf(Dv[ct][pt][0]+tb[0],0.f)*cb[0])
                    | ((unsigned)f2bf(fmaxf(Dv[ct][pt][1]+tb[1],0.f)*cb[1]) << 16);
        unsigned hi = (unsigned)f2bf(fmaxf(Dv[ct][pt][2]+tb[2],0.f)*cb[2])
                    | ((unsigned)f2bf(fmaxf(Dv[ct][pt][3]+tb[3],0.f)*cb[3]) << 16);
        uint2 o4; o4.x=lo; o4.y=hi;
        *(uint2*)&Os[pix*LDK + cbase] = o4;
      }
    }
  }
  __syncthreads();
  gemmO(Wo2);
  __syncthreads();

  // ---- branch 1 (transposed branch; ctx indexed by (b,c,n)) ----
  gemmX(Wv1g);
  {
    #pragma unroll
    for(int ct=0;ct<4;ct++){
      int cbase = wv*64 + ct*16 + lq*4;
      float4 tvv = *(const float4*)&tv1[b*256 + cbase];
      float tb[4] = {tvv.x,tvv.y,tvv.z,tvv.w};
      #pragma unroll
      for(int pt=0;pt<4;pt++){
        int pix = pt*16 + lr;
        int n = n0 + pix;
        float4 cx = *(const float4*)&ctx1[(size_t)(b*256+n)*256 + cbase];
        float cb[4] = {cx.x,cx.y,cx.z,cx.w};
        unsigned lo = (unsigned)f2bf(fmaxf(Dv[ct][pt][0]+tb[0],0.f)*cb[0])
                    | ((unsigned)f2bf(fmaxf(Dv[ct][pt][1]+tb[1],0.f)*cb[1]) << 16);
        unsigned hi = (unsigned)f2bf(fmaxf(Dv[ct][pt][2]+tb[2],0.f)*cb[2])
                    | ((unsigned)f2bf(fmaxf(Dv[ct][pt][3]+tb[3],0.f)*cb[3]) << 16);
        uint2 o4; o4.x=lo; o4.y=hi;
        *(uint2*)&Os[pix*LDK + cbase] = o4;
      }
    }
  }
  __syncthreads();
  gemmO(Wo1);

  // ---- epilogue: xnew = y1 + y2 + bout1+bout2 + x; LN3 stats; emit fragment-blob bf16 copy ----
  float s3=0.f, ss3=0.f;
  #pragma unroll
  for(int ct=0;ct<4;ct++){
    int cbase = wv*64 + ct*16 + lq*4;
    float4 bsv = *(const float4*)&bsum[cbase];
    float bb[4] = {bsv.x,bsv.y,bsv.z,bsv.w};
    #pragma unroll
    for(int pt=0;pt<4;pt++){
      int pix = pt*16 + lr;
      size_t base = (size_t)b*4194304 + (size_t)cbase*16384 + (size_t)p*256 + n0 + pix;
      float vv[4];
      #pragma unroll
      for(int r=0;r<4;r++){
        size_t a = base + (size_t)r*16384;
        float v = Dy[ct][pt][r] + bb[r] + x[a];
        out[a] = v;
        vv[r] = v;
        s3 += v; ss3 += v*v;
      }
      if(xb){
        uint2 pk;
        pk.x = (unsigned)f2bf(vv[0]) | ((unsigned)f2bf(vv[1]) << 16);
        pk.y = (unsigned)f2bf(vv[2]) | ((unsigned)f2bf(vv[3]) << 16);
        // fragment-blob address: blob = b*1024 + p*16 + (n0>>4) + pt ; chunk = cbase>>5
        size_t fo = ((size_t)(b*1024 + p*16 + ((bid&3)<<2) + pt) << 12)
                  + (size_t)(wv*2 + (ct>>1))*512
                  + (size_t)((((ct&1)*2 + (lq>>1))*16 + lr)*8) + (lq&1)*4;
        *(uint2*)&xb[fo] = pk;
      }
    }
  }
  for(int off=32; off; off>>=1){ s3 += __shfl_down(s3,off,64); ss3 += __shfl_down(ss3,off,64); }
  if(lane==0){ rs[wv]=s3; rss[wv]=ss3; }
  __syncthreads();
  if(tid==0){
    atomicAdd(&stats[32+b], rs[0]+rs[1]+rs[2]+rs[3]);
    atomicAdd(&stats[48+b], rss[0]+rss[1]+rss[2]+rss[3]);
  }
}

__global__ void k_finalize3(const float* __restrict__ stats, float* __restrict__ derived,
                            const float* __restrict__ bf1, const float* __restrict__ A3,
                            const float* __restrict__ B3, float* __restrict__ t3)
{
  int tid = threadIdx.x;
  if(tid < 16){
    float M = 4194304.f;
    float mean = stats[32+tid]/M;
    float var  = stats[48+tid]/M - mean*mean;
    derived[32+tid] = mean;
    derived[48+tid] = rsqrtf(var + 1e-5f);
  }
  __syncthreads();
  float a = A3[tid], bb = B3[tid], bias = bf1[tid];
  for(int b=0;b<16;b++){
    float mr = derived[32+b]*derived[48+b];
    t3[b*512 + tid] = bias + bb - mr*a;
  }
}

// ---------------- pass 6 (fast): FFN with fragment-blob xb staged once into linear LDS ----------------
// One HBM-latency wait per block (coalesced 16KB stage); both GEMMs read B from conflict-free LDS.
// h is written back to LDS in fragment order (overwriting the dead X stage). LDS total = 32 KB.
__global__ __launch_bounds__(256,4) void k_ffn2(
    const u16* __restrict__ xb,
    const u16* __restrict__ Wf1g, const u16* __restrict__ Wf2b,
    const float* __restrict__ t3, const float* __restrict__ bf2,
    const float* __restrict__ derived,
    float* __restrict__ out)
{
  __shared__ __align__(16) u16 S[16384];   // 32 KB: [0,8192)=X frags during GEMM-h; full = h frags for GEMM-y
  int bid = blockIdx.x;
  int b = bid >> 9, p = (bid >> 3) & 63, n0 = (bid & 7) << 5;
  int tid = threadIdx.x, wv = tid >> 6, lane = tid & 63, lr = lane & 15, lq = lane >> 4;
  float rstd = derived[48+b];

  { // stage 2 contiguous blobs (16 KB) -> linear LDS, fully coalesced
    const u16* gsrc = xb + ((size_t)(b*1024 + p*16 + ((bid&7)<<1)) << 12);
    #pragma unroll
    for(int i=0;i<4;i++)
      *(uint4*)&S[i*2048 + tid*8] = *(const uint4*)&gsrc[i*2048 + tid*8];
  }
  __syncthreads();

  // GEMM-h: Dh[8][2], f = wv*128 + ct*16; B = conflict-free fragment reads from LDS
  floatx4 Dh[8][2];
  #pragma unroll
  for(int i=0;i<8;i++){ Dh[i][0] = floatx4{0.f,0.f,0.f,0.f}; Dh[i][1] = floatx4{0.f,0.f,0.f,0.f}; }
  for(int k0=0;k0<256;k0+=32){
    bf16x8 Bf[2];
    #pragma unroll
    for(int pt=0;pt<2;pt++) Bf[pt] = *(const bf16x8*)&S[pt*4096 + (k0>>5)*512 + lane*8];
    #pragma unroll
    for(int ct=0;ct<8;ct++){
      bf16x8 Af = *(const bf16x8*)&Wf1g[(size_t)(wv*128+ct*16+lr)*256 + k0 + lq*8];
      Dh[ct][0] = MFMA16(Af, Bf[0], Dh[ct][0]);
      Dh[ct][1] = MFMA16(Af, Bf[1], Dh[ct][1]);
    }
  }
  __syncthreads();   // all X-fragment reads done; S can be overwritten

  // h = clip(rstd*Dh + t3, -1, 1) -> S in fragment order (contiguous 512B per instr, conflict-free)
  #pragma unroll
  for(int ct=0;ct<8;ct++){
    int fbase = wv*128 + ct*16 + lq*4;
    float4 tt = *(const float4*)&t3[b*512 + fbase];
    float tb[4] = {tt.x,tt.y,tt.z,tt.w};
    #pragma unroll
    for(int pt=0;pt<2;pt++){
      unsigned lo = (unsigned)f2bf(fminf(fmaxf(rstd*Dh[ct][pt][0]+tb[0],-1.f),1.f))
                  | ((unsigned)f2bf(fminf(fmaxf(rstd*Dh[ct][pt][1]+tb[1],-1.f),1.f)) << 16);
      unsigned hi = (unsigned)f2bf(fminf(fmaxf(rstd*Dh[ct][pt][2]+tb[2],-1.f),1.f))
                  | ((unsigned)f2bf(fminf(fmaxf(rstd*Dh[ct][pt][3]+tb[3],-1.f),1.f)) << 16);
      uint2 o4; o4.x=lo; o4.y=hi;
      int oi = pt*8192 + (wv*4 + (ct>>1))*512 + (((ct&1)*2 + (lq>>1))*16 + lr)*8 + (lq&1)*4;
      *(uint2*)&S[oi] = o4;
    }
  }
  __syncthreads();

  // GEMM-y: K=512, B = conflict-free fragment reads from LDS
  floatx4 Dy[4][2];
  #pragma unroll
  for(int i=0;i<4;i++){ Dy[i][0] = floatx4{0.f,0.f,0.f,0.f}; Dy[i][1] = floatx4{0.f,0.f,0.f,0.f}; }
  for(int k0=0;k0<512;k0+=32){
    bf16x8 Bf[2];
    #pragma unroll
    for(int pt=0;pt<2;pt++) Bf[pt] = *(const bf16x8*)&S[pt*8192 + (k0>>5)*512 + lane*8];
    #pragma unroll
    for(int ct=0;ct<4;ct++){
      bf16x8 Af = *(const bf16x8*)&Wf2b[(size_t)(wv*64+ct*16+lr)*512 + k0 + lq*8];
      Dy[ct][0] = MFMA16(Af, Bf[0], Dy[ct][0]);
      Dy[ct][1] = MFMA16(Af, Bf[1], Dy[ct][1]);
    }
  }

  // epilogue: out = xnew + y + bf2 (read-before-write, same thread per element)
  #pragma unroll
  for(int ct=0;ct<4;ct++){
    int obase = wv*64 + ct*16 + lq*4;
    float4 bbv = *(const float4*)&bf2[obase];
    float bb[4] = {bbv.x,bbv.y,bbv.z,bbv.w};
    #pragma unroll
    for(int pt=0;pt<2;pt++){
      int pix = pt*16 + lr;
      size_t base = (size_t)b*4194304 + (size_t)obase*16384 + (size_t)p*256 + n0 + pix;
      #pragma unroll
      for(int r=0;r<4;r++){
        size_t a = base + (size_t)r*16384;
        out[a] = out[a] + Dy[ct][pt][r] + bb[r];
      }
    }
  }
}

// ---------------- pass 6 (fallback, if workspace too small for xb): original staging version ----------------
__global__ __launch_bounds__(256,2) void k_ffn(
    const u16* __restrict__ Wf1g, const u16* __restrict__ Wf2b,
    const float* __restrict__ t3, const float* __restrict__ bf2,
    const float* __restrict__ derived,
    float* __restrict__ out)
{
  __shared__ u16 Xs[32*LDK];
  __shared__ u16 Os[32*LDO];
  int bid = blockIdx.x;
  int b = bid >> 9, p = (bid >> 3) & 63, n0 = (bid & 7) << 5;
  int tid = threadIdx.x, wv = tid >> 6, lane = tid & 63, lr = lane & 15, lq = lane >> 4;
  float rstd = derived[48+b];

  { // stage X3' = bf16(rstd3 * xnew)
    int pix = tid & 31, c0 = (tid >> 5) * 2;
    const float* xp = out + ((size_t)b*4194304 + (size_t)p*256 + n0 + pix);
    for(int cc = c0; cc < 256; cc += 16){
      float v0 = xp[(size_t)cc*16384];
      float v1 = xp[(size_t)(cc+1)*16384];
      unsigned pk = (unsigned)f2bf(rstd*v0) | ((unsigned)f2bf(rstd*v1) << 16);
      *(unsigned*)&Xs[pix*LDK + cc] = pk;
    }
  }
  __syncthreads();

  floatx4 Dh[8][2];
  #pragma unroll
  for(int i=0;i<8;i++){ Dh[i][0] = floatx4{0.f,0.f,0.f,0.f}; Dh[i][1] = floatx4{0.f,0.f,0.f,0.f}; }
  for(int k0=0;k0<256;k0+=32){
    bf16x8 Bf[2];
    #pragma unroll
    for(int pt=0;pt<2;pt++) Bf[pt] = *(const bf16x8*)&Xs[(pt*16+lr)*LDK + k0 + lq*8];
    #pragma unroll
    for(int ct=0;ct<8;ct++){
      bf16x8 Af = *(const bf16x8*)&Wf1g[(size_t)(wv*128+ct*16+lr)*256 + k0 + lq*8];
      Dh[ct][0] = MFMA16(Af, Bf[0], Dh[ct][0]);
      Dh[ct][1] = MFMA16(Af, Bf[1], Dh[ct][1]);
    }
  }
  #pragma unroll
  for(int ct=0;ct<8;ct++){
    int fbase = wv*128 + ct*16 + lq*4;
    float4 tt = *(const float4*)&t3[b*512 + fbase];
    float tb[4] = {tt.x,tt.y,tt.z,tt.w};
    #pragma unroll
    for(int pt=0;pt<2;pt++){
      int pix = pt*16 + lr;
      unsigned lo = (unsigned)f2bf(fminf(fmaxf(Dh[ct][pt][0]+tb[0],-1.f),1.f))
                  | ((unsigned)f2bf(fminf(fmaxf(Dh[ct][pt][1]+tb[1],-1.f),1.f)) << 16);
      unsigned hi = (unsigned)f2bf(fminf(fmaxf(Dh[ct][pt][2]+tb[2],-1.f),1.f))
                  | ((unsigned)f2bf(fminf(fmaxf(Dh[ct][pt][3]+tb[3],-1.f),1.f)) << 16);
      uint2 o4; o4.x=lo; o4.y=hi;
      *(uint2*)&Os[pix*LDO + fbase] = o4;
    }
  }
  __syncthreads();

  floatx4 Dy[4][2];
  #pragma unroll
  for(int i=0;i<4;i++){ Dy[i][0] = floatx4{0.f,0.f,0.f,0.f}; Dy[i][1] = floatx4{0.f,0.f,0.f,0.f}; }
  for(int k0=0;k0<512;k0+=32){
    bf16x8 Bf[2];
    #pragma unroll
    for(int pt=0;pt<2;pt++) Bf[pt] = *(const bf16x8*)&Os[(pt*16+lr)*LDO + k0 + lq*8];
    #pragma unroll
    for(int ct=0;ct<4;ct++){
      bf16x8 Af = *(const bf16x8*)&Wf2b[(size_t)(wv*64+ct*16+lr)*512 + k0 + lq*8];
      Dy[ct][0] = MFMA16(Af, Bf[0], Dy[ct][0]);
      Dy[ct][1] = MFMA16(Af, Bf[1], Dy[ct][1]);
    }
  }

  #pragma unroll
  for(int ct=0;ct<4;ct++){
    int obase = wv*64 + ct*16 + lq*4;
    float4 bbv = *(const float4*)&bf2[obase];
    float bb[4] = {bbv.x,bbv.y,bbv.z,bbv.w};
    #pragma unroll
    for(int pt=0;pt<2;pt++){
      int pix = pt*16 + lr;
      size_t base = (size_t)b*4194304 + (size_t)obase*16384 + (size_t)p*256 + n0 + pix;
      #pragma unroll
      for(int r=0;r<4;r++){
        size_t a = base + (size_t)r*16384;
        out[a] = out[a] + Dy[ct][pt][r] + bb[r];
      }
    }
  }
}

// ---------------- launcher ----------------
extern "C" void kernel_launch(void* const* d_in, const int* in_sizes, int n_in,
                              void* d_out, int out_size, void* d_ws, size_t ws_size,
                              hipStream_t stream)
{
  const float* x     = (const float*)d_in[0];
  const float* g1    = (const float*)d_in[1];
  const float* b1    = (const float*)d_in[2];
  const float* Wqkv1 = (const float*)d_in[3];
  const float* bqkv1 = (const float*)d_in[4];
  const float* Wout1 = (const float*)d_in[5];
  const float* bout1 = (const float*)d_in[6];
  const float* g2    = (const float*)d_in[7];
  const float* b2    = (const float*)d_in[8];
  const float* Wqkv2 = (const float*)d_in[9];
  const float* bqkv2 = (const float*)d_in[10];
  const float* Wout2 = (const float*)d_in[11];
  const float* bout2 = (const float*)d_in[12];
  const float* gf    = (const float*)d_in[13];
  const float* bfv   = (const float*)d_in[14];
  const float* Wf1   = (const float*)d_in[15];
  const float* bf1   = (const float*)d_in[16];
  const float* Wf2   = (const float*)d_in[17];
  const float* bf2   = (const float*)d_in[18];
  float* out = (float*)d_out;
  char* ws = (char*)d_ws;

  float* stats   = (float*)(ws + 0);          // 64 f (zeroed)
  float* derived = (float*)(ws + 256);        // 64 f
  float* bsum    = (float*)(ws + 512);        // 256 f
  float* Ak1 = (float*)(ws + 1536);
  float* Bk1 = (float*)(ws + 2560);
  float* Av1 = (float*)(ws + 3584);
  float* Bv1 = (float*)(ws + 4608);
  float* Ak2 = (float*)(ws + 5632);
  float* Bk2 = (float*)(ws + 6656);
  float* Av2 = (float*)(ws + 7680);
  float* Bv2 = (float*)(ws + 8704);
  float* A3  = (float*)(ws + 9728);
  float* B3  = (float*)(ws + 11776);
  float* tk1 = (float*)(ws + 13824);
  float* tv1 = (float*)(ws + 30208);
  float* tk2 = (float*)(ws + 46592);
  float* tv2 = (float*)(ws + 62976);
  float* t3  = (float*)(ws + 79360);
  float* Wk1g = (float*)(ws + 112128);
  float* Wk2g = (float*)(ws + 374272);
  u16* Wv1g = (u16*)(ws + 636416);
  u16* Wv2g = (u16*)(ws + 767488);
  u16* Wo1  = (u16*)(ws + 898560);
  u16* Wo2  = (u16*)(ws + 1029632);
  u16* Wf1g = (u16*)(ws + 1160704);
  u16* Wf2b = (u16*)(ws + 1422848);
  float* rawq1   = (float*)(ws + 1684992);
  float* rawq2   = (float*)(ws + 2733568);
  float* scores1 = (float*)(ws + 3782144);
  float* scores2 = (float*)(ws + 4830720);
  float* xs1  = (float*)(ws + 5879296);
  float* xs2  = (float*)(ws + 10073600);
  float* ctx1 = (float*)(ws + 11122176);
  float* ctx2 = (float*)(ws + 15316480);
  // xb: bf16(xnew) in fragment-blob order, 16*16384*256*2 = 128 MiB, at 16 MiB offset
  const size_t XB_OFF  = 16777216;
  const size_t XB_SIZE = (size_t)16*16384*256*2;
  bool fast = (ws_size >= XB_OFF + XB_SIZE);
  u16* xb = fast ? (u16*)(ws + XB_OFF) : (u16*)nullptr;

  hipMemsetAsync(stats, 0, 64*sizeof(float), stream);

  k_prep<<<2304, 256, 0, stream>>>(Wqkv1,g1,b1, Wqkv2,g2,b2, Wout1,Wout2, Wf1,gf,bfv, Wf2, bout1,bout2,
                                   Wk1g,Wk2g, Wv1g,Wv2g,Wo1,Wo2,Wf1g,Wf2b,
                                   Ak1,Bk1,Av1,Bv1, Ak2,Bk2,Av2,Bv2, A3,B3, bsum);
  k_stats_q<<<256, 256, 0, stream>>>(x, Wqkv1,g1, Wqkv2,g2, stats, rawq1, rawq2);
  k_finalize<<<1, 64, 0, stream>>>(stats, derived);
  k_tvec<<<16, 256, 0, stream>>>(derived, bqkv1,bqkv2, Ak1,Bk1,Av1,Bv1, Ak2,Bk2,Av2,Bv2,
                                 tk1,tv1,tk2,tv2);
  k_softmax2<<<1024, 256, 0, stream>>>(rawq2, derived, scores2);
  k_softmax1<<<4096, 64, 0, stream>>>(rawq1, derived, scores1);
  k_xs<<<4096, 256, 0, stream>>>(x, scores1, scores2, xs1, xs2);
  k_ctx2<<<256, 256, 0, stream>>>(Wk2g, xs2, tk2, derived, ctx2);
  k_ctx1<<<1024, 256, 0, stream>>>(Wk1g, xs1, tk1, derived, ctx1);
  k_attn<<<4096, 256, 0, stream>>>(x, Wv1g,Wv2g, Wo1,Wo2, tv1,tv2, ctx1,ctx2,
                                   bsum, derived, out, stats, xb);
  k_finalize3<<<1, 512, 0, stream>>>(stats, derived, bf1, A3, B3, t3);
  if(fast)
    k_ffn2<<<8192, 256, 0, stream>>>(xb, Wf1g, Wf2b, t3, bf2, derived, out);
  else
    k_ffn<<<8192, 256, 0, stream>>>(Wf1g, Wf2b, t3, bf2, derived, out);
}

// Round 3
// 1631.800 us; speedup vs baseline: 1.0374x; 1.0126x over previous
//
#include <hip/hip_runtime.h>

typedef __bf16 bf16x8 __attribute__((ext_vector_type(8)));
typedef float floatx4 __attribute__((ext_vector_type(4)));
typedef unsigned short u16;

#define MFMA16(A,Bv,Cv) __builtin_amdgcn_mfma_f32_16x16x32_bf16(A,Bv,Cv,0,0,0)

__device__ __forceinline__ u16 f2bf(float f){
  unsigned u = __float_as_uint(f);
  return (u16)((u + 0x7fffu + ((u >> 16) & 1u)) >> 16);
}

#define LDK 264   // u16 row stride for [pix][k] LDS tiles (K=256 + 8 pad -> 2-way-free banks)
#define LDO 520   // u16 row stride for K=512 tile

// ---------------- weight prep: fold LN gamma into weights, bf16-convert, row sums ----------------
__global__ void k_prep(const float* __restrict__ Wqkv1, const float* __restrict__ g1, const float* __restrict__ b1,
                       const float* __restrict__ Wqkv2, const float* __restrict__ g2, const float* __restrict__ b2,
                       const float* __restrict__ Wout1, const float* __restrict__ Wout2,
                       const float* __restrict__ Wf1, const float* __restrict__ gf, const float* __restrict__ bfv,
                       const float* __restrict__ Wf2, const float* __restrict__ bout1, const float* __restrict__ bout2,
                       float* __restrict__ Wk1g, float* __restrict__ Wk2g,
                       u16* __restrict__ Wv1g, u16* __restrict__ Wv2g, u16* __restrict__ Wo1, u16* __restrict__ Wo2,
                       u16* __restrict__ Wf1g, u16* __restrict__ Wf2b,
                       float* __restrict__ Ak1, float* __restrict__ Bk1, float* __restrict__ Av1, float* __restrict__ Bv1,
                       float* __restrict__ Ak2, float* __restrict__ Bk2, float* __restrict__ Av2, float* __restrict__ Bv2,
                       float* __restrict__ A3, float* __restrict__ B3, float* __restrict__ bsum)
{
  int bid = blockIdx.x, c = threadIdx.x;
  __shared__ float sa[4], sb[4];
  int wv = c >> 6, ln = c & 63;
  auto rowsum2 = [&](float a, float bb, float* pA, float* pB){
    for(int off=32; off; off>>=1){ a += __shfl_down(a,off,64); bb += __shfl_down(bb,off,64); }
    if(ln==0){ sa[wv]=a; sb[wv]=bb; }
    __syncthreads();
    if(c==0){ *pA = sa[0]+sa[1]+sa[2]+sa[3]; *pB = sb[0]+sb[1]+sb[2]+sb[3]; }
  };
  if(bid < 512){
    int r = bid; float w = Wqkv1[(size_t)(1+r)*256 + c];
    if(r < 256){ float wg = w*g1[c]; Wk1g[(size_t)r*256+c] = wg; rowsum2(wg, w*b1[c], &Ak1[r], &Bk1[r]); }
    else { int rv=r-256; float wg=w*g1[c]; Wv1g[(size_t)rv*256+c] = f2bf(wg); rowsum2(wg, w*b1[c], &Av1[rv], &Bv1[rv]); }
  } else if(bid < 1024){
    int r = bid-512; float w = Wqkv2[(size_t)(1+r)*256 + c];
    if(r < 256){ float wg = w*g2[c]; Wk2g[(size_t)r*256+c] = wg; rowsum2(wg, w*b2[c], &Ak2[r], &Bk2[r]); }
    else { int rv=r-256; float wg=w*g2[c]; Wv2g[(size_t)rv*256+c] = f2bf(wg); rowsum2(wg, w*b2[c], &Av2[rv], &Bv2[rv]); }
  } else if(bid < 1280){
    int r = bid-1024; Wo1[(size_t)r*256+c] = f2bf(Wout1[(size_t)r*256+c]);
    if(bid==1024) bsum[c] = bout1[c] + bout2[c];
  } else if(bid < 1536){
    int r = bid-1280; Wo2[(size_t)r*256+c] = f2bf(Wout2[(size_t)r*256+c]);
  } else if(bid < 2048){
    int r = bid-1536; float w = Wf1[(size_t)r*256+c]; float wg = w*gf[c];
    Wf1g[(size_t)r*256+c] = f2bf(wg); rowsum2(wg, w*bfv[c], &A3[r], &B3[r]);
  } else {
    int r = bid-2048;
    Wf2b[(size_t)r*512+c]     = f2bf(Wf2[(size_t)r*512+c]);
    Wf2b[(size_t)r*512+256+c] = f2bf(Wf2[(size_t)r*512+256+c]);
  }
}

// ---------------- pass 1: per-batch sum/sumsq + raw q for both branches ----------------
__global__ void k_stats_q(const float* __restrict__ x,
                          const float* __restrict__ Wqkv1, const float* __restrict__ g1,
                          const float* __restrict__ Wqkv2, const float* __restrict__ g2,
                          float* __restrict__ stats,
                          float* __restrict__ rawq1, float* __restrict__ rawq2)
{
  int bid = blockIdx.x; int b = bid >> 4, chunk = bid & 15;
  int tid = threadIdx.x;
  __shared__ float wq1[256], wq2[256];
  __shared__ float sred[4], ssred[4];
  wq1[tid] = Wqkv1[tid]*g1[tid];   // row 0 of Wqkv = q projection
  wq2[tid] = Wqkv2[tid]*g2[tid];
  __syncthreads();
  int pix0 = chunk*1024 + tid*4;             // 4 consecutive pixels, same p
  int p = pix0 >> 8, n = pix0 & 255;
  const float* xp = x + ((size_t)b << 22) + pix0;
  float s = 0.f, ss = 0.f;
  floatx4 q1 = {0.f,0.f,0.f,0.f}, q2 = {0.f,0.f,0.f,0.f};
  #pragma unroll 4
  for(int c=0;c<256;c++){
    floatx4 v = *(const floatx4*)&xp[(size_t)c << 14];
    s  += v[0]+v[1]+v[2]+v[3];
    ss += v[0]*v[0]+v[1]*v[1]+v[2]*v[2]+v[3]*v[3];
    q1 += wq1[c]*v;
    q2 += wq2[c]*v;
  }
  *(floatx4*)&rawq2[(size_t)(b*64 + p)*256 + n] = q2;      // [b][p][n]
  #pragma unroll
  for(int i=0;i<4;i++) rawq1[((size_t)(b*256 + n + i))*64 + p] = q1[i];  // [b][n][p]
  int wv = tid>>6, ln = tid&63;
  for(int off=32; off; off>>=1){ s += __shfl_down(s,off,64); ss += __shfl_down(ss,off,64); }
  if(ln==0){ sred[wv]=s; ssred[wv]=ss; }
  __syncthreads();
  if(tid==0){
    atomicAdd(&stats[b],    sred[0]+sred[1]+sred[2]+sred[3]);
    atomicAdd(&stats[16+b], ssred[0]+ssred[1]+ssred[2]+ssred[3]);
  }
}

__global__ void k_finalize(const float* __restrict__ stats, float* __restrict__ derived)
{
  int b = threadIdx.x;
  if(b < 16){
    float M = 4194304.f;
    float mean = stats[b]/M;
    float var  = stats[16+b]/M - mean*mean;
    derived[b] = mean;
    derived[16+b] = rsqrtf(var + 1e-5f);
  }
}

// t[b,o] = bias[o] + sum_c W[o,c]*beta[c] - mean_b*rstd_b*sum_c W[o,c]*g[c]
__global__ void k_tvec(const float* __restrict__ derived,
                       const float* __restrict__ bqkv1, const float* __restrict__ bqkv2,
                       const float* __restrict__ Ak1, const float* __restrict__ Bk1,
                       const float* __restrict__ Av1, const float* __restrict__ Bv1,
                       const float* __restrict__ Ak2, const float* __restrict__ Bk2,
                       const float* __restrict__ Av2, const float* __restrict__ Bv2,
                       float* __restrict__ tk1, float* __restrict__ tv1,
                       float* __restrict__ tk2, float* __restrict__ tv2)
{
  int b = blockIdx.x, c = threadIdx.x;
  float mr = derived[b]*derived[16+b];
  tk1[b*256+c] = bqkv1[1+c]   + Bk1[c] - mr*Ak1[c];
  tv1[b*256+c] = bqkv1[257+c] + Bv1[c] - mr*Av1[c];
  tk2[b*256+c] = bqkv2[1+c]   + Bk2[c] - mr*Ak2[c];
  tv2[b*256+c] = bqkv2[257+c] + Bv2[c] - mr*Av2[c];
}

// softmax over N for rows (b,p)
__global__ void k_softmax2(const float* __restrict__ rawq2, const float* __restrict__ derived,
                           float* __restrict__ scores2)
{
  int row = blockIdx.x; int b = row >> 6; int tid = threadIdx.x;
  __shared__ float sm[4], ssum[4];
  int wv = tid>>6, ln = tid&63;
  float v = derived[16+b]*rawq2[(size_t)row*256 + tid];
  float m = v;
  for(int off=32; off; off>>=1) m = fmaxf(m, __shfl_xor(m,off,64));
  if(ln==0) sm[wv]=m;
  __syncthreads();
  m = fmaxf(fmaxf(sm[0],sm[1]),fmaxf(sm[2],sm[3]));
  float e = __expf(v-m);
  float s = e;
  for(int off=32; off; off>>=1) s += __shfl_xor(s,off,64);
  if(ln==0) ssum[wv]=s;
  __syncthreads();
  s = ssum[0]+ssum[1]+ssum[2]+ssum[3];
  scores2[(size_t)row*256 + tid] = e/s;
}

// softmax over P (64) for rows (b,n) -- one wave
__global__ void k_softmax1(const float* __restrict__ rawq1, const float* __restrict__ derived,
                           float* __restrict__ scores1)
{
  int row = blockIdx.x; int b = row >> 8; int tid = threadIdx.x;
  float v = derived[16+b]*rawq1[(size_t)row*64 + tid];
  float m = v;
  for(int off=32; off; off>>=1) m = fmaxf(m, __shfl_xor(m,off,64));
  float e = __expf(v-m);
  float s = e;
  for(int off=32; off; off>>=1) s += __shfl_xor(s,off,64);
  scores1[(size_t)row*64 + tid] = e/s;
}

// pass 3: xs1[b][c][n] = sum_p S1*x ; xs2[b][c][p] = sum_n S2*x
__global__ void k_xs(const float* __restrict__ x,
                     const float* __restrict__ scores1, const float* __restrict__ scores2,
                     float* __restrict__ xs1, float* __restrict__ xs2)
{
  __shared__ float X[64*257];
  __shared__ float part[256];
  int bid = blockIdx.x; int b = bid >> 8, c = bid & 255;
  int tid = threadIdx.x;
  const float* xp = x + ((size_t)b*4194304 + (size_t)c*16384);
  for(int i=tid; i<16384; i+=256){
    int p = i >> 8, n = i & 255;
    X[p*257 + n] = xp[i];
  }
  __syncthreads();
  {
    int n = tid;
    const float* s1 = scores1 + (size_t)(b*256 + n)*64;
    float acc = 0.f;
    #pragma unroll 8
    for(int p=0;p<64;p++) acc += s1[p]*X[p*257+n];
    xs1[(size_t)(b*256 + c)*256 + n] = acc;
  }
  {
    int p = tid & 63, q = tid >> 6;
    const float* s2 = scores2 + (size_t)(b*64 + p)*256;
    float acc = 0.f;
    #pragma unroll 8
    for(int i=0;i<64;i++){ int n = q*64 + i; acc += s2[n]*X[p*257+n]; }
    part[tid] = acc;
    __syncthreads();
    if(q==0)
      xs2[(size_t)(b*256 + c)*64 + p] = part[p] + part[64+p] + part[128+p] + part[192+p];
  }
}

// ctx2[b][p][o] = rstd*(Wk2g@xs2) + tk2  (store pixel-major so pass5 reads float4 over o)
__global__ void k_ctx2(const float* __restrict__ Wk2g, const float* __restrict__ xs2,
                       const float* __restrict__ tk2, const float* __restrict__ derived,
                       float* __restrict__ ctx2)
{
  __shared__ float xv[4][256];
  int bid = blockIdx.x; int b = bid >> 4, pg = (bid & 15) << 2;
  int o = threadIdx.x;
  #pragma unroll
  for(int j=0;j<4;j++) xv[j][o] = xs2[(size_t)(b*256 + o)*64 + pg + j];
  __syncthreads();
  const float* w = Wk2g + (size_t)o*256;
  float a0=0,a1=0,a2=0,a3=0;
  for(int cc=0;cc<256;cc++){
    float wc = w[cc];
    a0 += wc*xv[0][cc]; a1 += wc*xv[1][cc]; a2 += wc*xv[2][cc]; a3 += wc*xv[3][cc];
  }
  float r = derived[16+b], t = tk2[b*256 + o];
  ctx2[(size_t)(b*64 + pg+0)*256 + o] = r*a0 + t;
  ctx2[(size_t)(b*64 + pg+1)*256 + o] = r*a1 + t;
  ctx2[(size_t)(b*64 + pg+2)*256 + o] = r*a2 + t;
  ctx2[(size_t)(b*64 + pg+3)*256 + o] = r*a3 + t;
}

__global__ void k_ctx1(const float* __restrict__ Wk1g, const float* __restrict__ xs1,
                       const float* __restrict__ tk1, const float* __restrict__ derived,
                       float* __restrict__ ctx1)
{
  __shared__ float xv[4][256];
  int bid = blockIdx.x; int b = bid >> 6, ng = (bid & 63) << 2;
  int o = threadIdx.x;
  #pragma unroll
  for(int j=0;j<4;j++) xv[j][o] = xs1[(size_t)(b*256 + o)*256 + ng + j];
  __syncthreads();
  const float* w = Wk1g + (size_t)o*256;
  float a0=0,a1=0,a2=0,a3=0;
  for(int cc=0;cc<256;cc++){
    float wc = w[cc];
    a0 += wc*xv[0][cc]; a1 += wc*xv[1][cc]; a2 += wc*xv[2][cc]; a3 += wc*xv[3][cc];
  }
  float r = derived[16+b], t = tk1[b*256 + o];
  ctx1[(size_t)(b*256 + ng+0)*256 + o] = r*a0 + t;
  ctx1[(size_t)(b*256 + ng+1)*256 + o] = r*a1 + t;
  ctx1[(size_t)(b*256 + ng+2)*256 + o] = r*a2 + t;
  ctx1[(size_t)(b*256 + ng+3)*256 + o] = r*a3 + t;
}

// ---------------- pass 5: both attention branches fused, MFMA bf16 ----------------
// block = (b, p, 64 n's). v-GEMMs on rstd*x, relu*ctx, Wout GEMMs, +residual -> out (=xnew), LN3 stats.
// Emits xb = bf16(xnew) in MFMA-fragment-blob order:
//   blob g = global_pixel/16 (16 pixels); within blob: [chunk=c/32][lane][8 ch * 2B]
//   -> a wave's B-fragment at k0 is the contiguous 1KB at g*8192 + (k0/32)*1024 + lane*16.
__global__ __launch_bounds__(256,2) void k_attn(
    const float* __restrict__ x,
    const u16* __restrict__ Wv1g, const u16* __restrict__ Wv2g,
    const u16* __restrict__ Wo1, const u16* __restrict__ Wo2,
    const float* __restrict__ tv1, const float* __restrict__ tv2,
    const float* __restrict__ ctx1, const float* __restrict__ ctx2,
    const float* __restrict__ bsum, const float* __restrict__ derived,
    float* __restrict__ out, float* __restrict__ stats,
    u16* __restrict__ xb)
{
  __shared__ u16 Xs[64*LDK];
  __shared__ u16 Os[64*LDK];
  __shared__ float rs[4], rss[4];
  int bid = blockIdx.x;
  int b = bid >> 8, p = (bid >> 2) & 63, n0 = (bid & 3) << 6;
  int tid = threadIdx.x, wv = tid >> 6, lane = tid & 63, lr = lane & 15, lq = lane >> 4;
  float rstd = derived[16+b];

  { // stage X' = bf16(rstd*x) as [pix][k]
    int pix = tid & 63, c0 = (tid >> 6) * 2;
    const float* xp = x + ((size_t)b*4194304 + (size_t)p*256 + n0 + pix);
    for(int cc = c0; cc < 256; cc += 8){
      float v0 = xp[(size_t)cc*16384];
      float v1 = xp[(size_t)(cc+1)*16384];
      unsigned pk = (unsigned)f2bf(rstd*v0) | ((unsigned)f2bf(rstd*v1) << 16);
      *(unsigned*)&Xs[pix*LDK + cc] = pk;
    }
  }
  __syncthreads();

  floatx4 Dv[4][4], Dy[4][4];
  #pragma unroll
  for(int i=0;i<4;i++){
    #pragma unroll
    for(int j=0;j<4;j++) Dy[i][j] = floatx4{0.f,0.f,0.f,0.f};
  }

  auto gemmX = [&](const u16* __restrict__ W){   // Dv = W @ Xs
    #pragma unroll
    for(int i=0;i<4;i++){
      #pragma unroll
      for(int j=0;j<4;j++) Dv[i][j] = floatx4{0.f,0.f,0.f,0.f};
    }
    for(int k0=0;k0<256;k0+=32){
      bf16x8 Bf[4];
      #pragma unroll
      for(int pt=0;pt<4;pt++) Bf[pt] = *(const bf16x8*)&Xs[(pt*16+lr)*LDK + k0 + lq*8];
      #pragma unroll
      for(int ct=0;ct<4;ct++){
        bf16x8 Af = *(const bf16x8*)&W[(size_t)(wv*64+ct*16+lr)*256 + k0 + lq*8];
        #pragma unroll
        for(int pt=0;pt<4;pt++) Dv[ct][pt] = MFMA16(Af, Bf[pt], Dv[ct][pt]);
      }
    }
  };
  auto gemmO = [&](const u16* __restrict__ W){   // Dy += W @ Os
    for(int k0=0;k0<256;k0+=32){
      bf16x8 Bf[4];
      #pragma unroll
      for(int pt=0;pt<4;pt++) Bf[pt] = *(const bf16x8*)&Os[(pt*16+lr)*LDK + k0 + lq*8];
      #pragma unroll
      for(int ct=0;ct<4;ct++){
        bf16x8 Af = *(const bf16x8*)&W[(size_t)(wv*64+ct*16+lr)*256 + k0 + lq*8];
        #pragma unroll
        for(int pt=0;pt<4;pt++) Dy[ct][pt] = MFMA16(Af, Bf[pt], Dy[ct][pt]);
      }
    }
  };

  // ---- branch 2 (no transpose; ctx indexed by (b,c,p)) ----
  gemmX(Wv2g);
  {
    const float* c2row = ctx2 + (size_t)(b*64+p)*256;
    #pragma unroll
    for(int ct=0;ct<4;ct++){
      int cbase = wv*64 + ct*16 + lq*4;
      float4 tvv = *(const float4*)&tv2[b*256 + cbase];
      float4 cx  = *(const float4*)&c2row[cbase];
      float tb[4] = {tvv.x,tvv.y,tvv.z,tvv.w};
      float cb[4] = {cx.x,cx.y,cx.z,cx.w};
      #pragma unroll
      for(int pt=0;pt<4;pt++){
        int pix = pt*16 + lr;
        unsigned lo = (unsigned)f2bf(fmaxf(Dv[ct][pt][0]+tb[0],0.f)*cb[0])
                    | ((unsigned)f2bf(fmaxf(Dv[ct][pt][1]+tb[1],0.f)*cb[1]) << 16);
        unsigned hi = (unsigned)f2bf(fmaxf(Dv[ct][pt][2]+tb[2],0.f)*cb[2])
                    | ((unsigned)f2bf(fmaxf(Dv[ct][pt][3]+tb[3],0.f)*cb[3]) << 16);
        uint2 o4; o4.x=lo; o4.y=hi;
        *(uint2*)&Os[pix*LDK + cbase] = o4;
      }
    }
  }
  __syncthreads();
  gemmO(Wo2);
  __syncthreads();

  // ---- branch 1 (transposed branch; ctx indexed by (b,c,n)) ----
  gemmX(Wv1g);
  {
    #pragma unroll
    for(int ct=0;ct<4;ct++){
      int cbase = wv*64 + ct*16 + lq*4;
      float4 tvv = *(const float4*)&tv1[b*256 + cbase];
      float tb[4] = {tvv.x,tvv.y,tvv.z,tvv.w};
      #pragma unroll
      for(int pt=0;pt<4;pt++){
        int pix = pt*16 + lr;
        int n = n0 + pix;
        float4 cx = *(const float4*)&ctx1[(size_t)(b*256+n)*256 + cbase];
        float cb[4] = {cx.x,cx.y,cx.z,cx.w};
        unsigned lo = (unsigned)f2bf(fmaxf(Dv[ct][pt][0]+tb[0],0.f)*cb[0])
                    | ((unsigned)f2bf(fmaxf(Dv[ct][pt][1]+tb[1],0.f)*cb[1]) << 16);
        unsigned hi = (unsigned)f2bf(fmaxf(Dv[ct][pt][2]+tb[2],0.f)*cb[2])
                    | ((unsigned)f2bf(fmaxf(Dv[ct][pt][3]+tb[3],0.f)*cb[3]) << 16);
        uint2 o4; o4.x=lo; o4.y=hi;
        *(uint2*)&Os[pix*LDK + cbase] = o4;
      }
    }
  }
  __syncthreads();
  gemmO(Wo1);

  // ---- epilogue: xnew = y1 + y2 + bout1+bout2 + x; LN3 stats; emit fragment-blob bf16 copy ----
  float s3=0.f, ss3=0.f;
  #pragma unroll
  for(int ct=0;ct<4;ct++){
    int cbase = wv*64 + ct*16 + lq*4;
    float4 bsv = *(const float4*)&bsum[cbase];
    float bb[4] = {bsv.x,bsv.y,bsv.z,bsv.w};
    #pragma unroll
    for(int pt=0;pt<4;pt++){
      int pix = pt*16 + lr;
      size_t base = (size_t)b*4194304 + (size_t)cbase*16384 + (size_t)p*256 + n0 + pix;
      float vv[4];
      #pragma unroll
      for(int r=0;r<4;r++){
        size_t a = base + (size_t)r*16384;
        float v = Dy[ct][pt][r] + bb[r] + x[a];
        out[a] = v;
        vv[r] = v;
        s3 += v; ss3 += v*v;
      }
      if(xb){
        uint2 pk;
        pk.x = (unsigned)f2bf(vv[0]) | ((unsigned)f2bf(vv[1]) << 16);
        pk.y = (unsigned)f2bf(vv[2]) | ((unsigned)f2bf(vv[3]) << 16);
        // fragment-blob address: blob = b*1024 + p*16 + (n0>>4) + pt ; chunk = cbase>>5
        size_t fo = ((size_t)(b*1024 + p*16 + ((bid&3)<<2) + pt) << 12)
                  + (size_t)(wv*2 + (ct>>1))*512
                  + (size_t)((((ct&1)*2 + (lq>>1))*16 + lr)*8) + (lq&1)*4;
        *(uint2*)&xb[fo] = pk;
      }
    }
  }
  for(int off=32; off; off>>=1){ s3 += __shfl_down(s3,off,64); ss3 += __shfl_down(ss3,off,64); }
  if(lane==0){ rs[wv]=s3; rss[wv]=ss3; }
  __syncthreads();
  if(tid==0){
    atomicAdd(&stats[32+b], rs[0]+rs[1]+rs[2]+rs[3]);
    atomicAdd(&stats[48+b], rss[0]+rss[1]+rss[2]+rss[3]);
  }
}

__global__ void k_finalize3(const float* __restrict__ stats, float* __restrict__ derived,
                            const float* __restrict__ bf1, const float* __restrict__ A3,
                            const float* __restrict__ B3, float* __restrict__ t3)
{
  int tid = threadIdx.x;
  if(tid < 16){
    float M = 4194304.f;
    float mean = stats[32+tid]/M;
    float var  = stats[48+tid]/M - mean*mean;
    derived[32+tid] = mean;
    derived[48+tid] = rsqrtf(var + 1e-5f);
  }
  __syncthreads();
  float a = A3[tid], bb = B3[tid], bias = bf1[tid];
  for(int b=0;b<16;b++){
    float mr = derived[32+b]*derived[48+b];
    t3[b*512 + tid] = bias + bb - mr*a;
  }
}

// ---------------- pass 6 (fast): FFN, 64-pixel tile -> 2x A-fragment reuse (pt=4) ----------------
// The L2 weight stream is the bottleneck (512B/MFMA at pt=2 caps MfmaUtil ~12%); pt=4 halves
// weight bytes per MFMA. X frags staged at S[0,32KB); h frags (64KB) overwrite S after GEMM-h.
__global__ __launch_bounds__(256,2) void k_ffn3(
    const u16* __restrict__ xb,
    const u16* __restrict__ Wf1g, const u16* __restrict__ Wf2b,
    const float* __restrict__ t3, const float* __restrict__ bf2,
    const float* __restrict__ derived,
    float* __restrict__ out)
{
  __shared__ __align__(16) u16 S[32768];   // 64 KB
  int bid = blockIdx.x;
  int b = bid >> 8, p = (bid >> 2) & 63, n0 = (bid & 3) << 6;
  int tid = threadIdx.x, wv = tid >> 6, lane = tid & 63, lr = lane & 15, lq = lane >> 4;
  float rstd = derived[48+b];

  { // stage 4 contiguous X-frag blobs (32 KB), fully coalesced
    const u16* gsrc = xb + ((size_t)(b*1024 + p*16 + (bid&3)*4) << 12);
    #pragma unroll
    for(int i=0;i<8;i++)
      *(uint4*)&S[i*2048 + tid*8] = *(const uint4*)&gsrc[i*2048 + tid*8];
  }
  __syncthreads();

  // GEMM-h: f = wv*128 + ct*16 (ct=0..7), pix groups pt=0..3 (64 pixels)
  floatx4 Dh[8][4];
  #pragma unroll
  for(int i=0;i<8;i++){
    #pragma unroll
    for(int j=0;j<4;j++) Dh[i][j] = floatx4{0.f,0.f,0.f,0.f};
  }
  for(int k0=0;k0<256;k0+=32){
    bf16x8 Bf[4];
    #pragma unroll
    for(int pt=0;pt<4;pt++) Bf[pt] = *(const bf16x8*)&S[pt*4096 + (k0>>5)*512 + lane*8];
    #pragma unroll
    for(int ct=0;ct<8;ct++){
      bf16x8 Af = *(const bf16x8*)&Wf1g[(size_t)(wv*128+ct*16+lr)*256 + k0 + lq*8];
      #pragma unroll
      for(int pt=0;pt<4;pt++) Dh[ct][pt] = MFMA16(Af, Bf[pt], Dh[ct][pt]);
    }
  }
  __syncthreads();   // all X reads done; S will be overwritten with h frags

  // h = clip(rstd*Dh + t3, -1, 1) -> S in h-frag-blob order [pixblob(4)][kstep(16)][lane][8]
  #pragma unroll
  for(int ct=0;ct<8;ct++){
    int fbase = wv*128 + ct*16 + lq*4;
    float4 tt = *(const float4*)&t3[b*512 + fbase];
    float tb[4] = {tt.x,tt.y,tt.z,tt.w};
    #pragma unroll
    for(int pt=0;pt<4;pt++){
      unsigned lo = (unsigned)f2bf(fminf(fmaxf(rstd*Dh[ct][pt][0]+tb[0],-1.f),1.f))
                  | ((unsigned)f2bf(fminf(fmaxf(rstd*Dh[ct][pt][1]+tb[1],-1.f),1.f)) << 16);
      unsigned hi = (unsigned)f2bf(fminf(fmaxf(rstd*Dh[ct][pt][2]+tb[2],-1.f),1.f))
                  | ((unsigned)f2bf(fminf(fmaxf(rstd*Dh[ct][pt][3]+tb[3],-1.f),1.f)) << 16);
      uint2 o4; o4.x=lo; o4.y=hi;
      int oi = pt*8192 + (wv*4 + (ct>>1))*512 + (((ct&1)*2 + (lq>>1))*16 + lr)*8 + (lq&1)*4;
      *(uint2*)&S[oi] = o4;
    }
  }
  __syncthreads();

  // GEMM-y: c = wv*64 + ct*16 (ct=0..3), pix pt=0..3, K=512
  floatx4 Dy[4][4];
  #pragma unroll
  for(int i=0;i<4;i++){
    #pragma unroll
    for(int j=0;j<4;j++) Dy[i][j] = floatx4{0.f,0.f,0.f,0.f};
  }
  for(int k0=0;k0<512;k0+=32){
    bf16x8 Bf[4];
    #pragma unroll
    for(int pt=0;pt<4;pt++) Bf[pt] = *(const bf16x8*)&S[pt*8192 + (k0>>5)*512 + lane*8];
    #pragma unroll
    for(int ct=0;ct<4;ct++){
      bf16x8 Af = *(const bf16x8*)&Wf2b[(size_t)(wv*64+ct*16+lr)*512 + k0 + lq*8];
      #pragma unroll
      for(int pt=0;pt<4;pt++) Dy[ct][pt] = MFMA16(Af, Bf[pt], Dy[ct][pt]);
    }
  }

  // epilogue: out = xnew + y + bf2 (read-before-write, same thread per element)
  #pragma unroll
  for(int ct=0;ct<4;ct++){
    int obase = wv*64 + ct*16 + lq*4;
    float4 bbv = *(const float4*)&bf2[obase];
    float bb[4] = {bbv.x,bbv.y,bbv.z,bbv.w};
    #pragma unroll
    for(int pt=0;pt<4;pt++){
      int pix = pt*16 + lr;
      size_t base = (size_t)b*4194304 + (size_t)obase*16384 + (size_t)p*256 + n0 + pix;
      #pragma unroll
      for(int r=0;r<4;r++){
        size_t a = base + (size_t)r*16384;
        out[a] = out[a] + Dy[ct][pt][r] + bb[r];
      }
    }
  }
}

// ---------------- pass 6 (fallback, if workspace too small for xb): original staging version ----------------
__global__ __launch_bounds__(256,2) void k_ffn(
    const u16* __restrict__ Wf1g, const u16* __restrict__ Wf2b,
    const float* __restrict__ t3, const float* __restrict__ bf2,
    const float* __restrict__ derived,
    float* __restrict__ out)
{
  __shared__ u16 Xs[32*LDK];
  __shared__ u16 Os[32*LDO];
  int bid = blockIdx.x;
  int b = bid >> 9, p = (bid >> 3) & 63, n0 = (bid & 7) << 5;
  int tid = threadIdx.x, wv = tid >> 6, lane = tid & 63, lr = lane & 15, lq = lane >> 4;
  float rstd = derived[48+b];

  { // stage X3' = bf16(rstd3 * xnew)
    int pix = tid & 31, c0 = (tid >> 5) * 2;
    const float* xp = out + ((size_t)b*4194304 + (size_t)p*256 + n0 + pix);
    for(int cc = c0; cc < 256; cc += 16){
      float v0 = xp[(size_t)cc*16384];
      float v1 = xp[(size_t)(cc+1)*16384];
      unsigned pk = (unsigned)f2bf(rstd*v0) | ((unsigned)f2bf(rstd*v1) << 16);
      *(unsigned*)&Xs[pix*LDK + cc] = pk;
    }
  }
  __syncthreads();

  floatx4 Dh[8][2];
  #pragma unroll
  for(int i=0;i<8;i++){ Dh[i][0] = floatx4{0.f,0.f,0.f,0.f}; Dh[i][1] = floatx4{0.f,0.f,0.f,0.f}; }
  for(int k0=0;k0<256;k0+=32){
    bf16x8 Bf[2];
    #pragma unroll
    for(int pt=0;pt<2;pt++) Bf[pt] = *(const bf16x8*)&Xs[(pt*16+lr)*LDK + k0 + lq*8];
    #pragma unroll
    for(int ct=0;ct<8;ct++){
      bf16x8 Af = *(const bf16x8*)&Wf1g[(size_t)(wv*128+ct*16+lr)*256 + k0 + lq*8];
      Dh[ct][0] = MFMA16(Af, Bf[0], Dh[ct][0]);
      Dh[ct][1] = MFMA16(Af, Bf[1], Dh[ct][1]);
    }
  }
  #pragma unroll
  for(int ct=0;ct<8;ct++){
    int fbase = wv*128 + ct*16 + lq*4;
    float4 tt = *(const float4*)&t3[b*512 + fbase];
    float tb[4] = {tt.x,tt.y,tt.z,tt.w};
    #pragma unroll
    for(int pt=0;pt<2;pt++){
      int pix = pt*16 + lr;
      unsigned lo = (unsigned)f2bf(fminf(fmaxf(Dh[ct][pt][0]+tb[0],-1.f),1.f))
                  | ((unsigned)f2bf(fminf(fmaxf(Dh[ct][pt][1]+tb[1],-1.f),1.f)) << 16);
      unsigned hi = (unsigned)f2bf(fminf(fmaxf(Dh[ct][pt][2]+tb[2],-1.f),1.f))
                  | ((unsigned)f2bf(fminf(fmaxf(Dh[ct][pt][3]+tb[3],-1.f),1.f)) << 16);
      uint2 o4; o4.x=lo; o4.y=hi;
      *(uint2*)&Os[pix*LDO + fbase] = o4;
    }
  }
  __syncthreads();

  floatx4 Dy[4][2];
  #pragma unroll
  for(int i=0;i<4;i++){ Dy[i][0] = floatx4{0.f,0.f,0.f,0.f}; Dy[i][1] = floatx4{0.f,0.f,0.f,0.f}; }
  for(int k0=0;k0<512;k0+=32){
    bf16x8 Bf[2];
    #pragma unroll
    for(int pt=0;pt<2;pt++) Bf[pt] = *(const bf16x8*)&Os[(pt*16+lr)*LDO + k0 + lq*8];
    #pragma unroll
    for(int ct=0;ct<4;ct++){
      bf16x8 Af = *(const bf16x8*)&Wf2b[(size_t)(wv*64+ct*16+lr)*512 + k0 + lq*8];
      Dy[ct][0] = MFMA16(Af, Bf[0], Dy[ct][0]);
      Dy[ct][1] = MFMA16(Af, Bf[1], Dy[ct][1]);
    }
  }

  #pragma unroll
  for(int ct=0;ct<4;ct++){
    int obase = wv*64 + ct*16 + lq*4;
    float4 bbv = *(const float4*)&bf2[obase];
    float bb[4] = {bbv.x,bbv.y,bbv.z,bbv.w};
    #pragma unroll
    for(int pt=0;pt<2;pt++){
      int pix = pt*16 + lr;
      size_t base = (size_t)b*4194304 + (size_t)obase*16384 + (size_t)p*256 + n0 + pix;
      #pragma unroll
      for(int r=0;r<4;r++){
        size_t a = base + (size_t)r*16384;
        out[a] = out[a] + Dy[ct][pt][r] + bb[r];
      }
    }
  }
}

// ---------------- launcher ----------------
extern "C" void kernel_launch(void* const* d_in, const int* in_sizes, int n_in,
                              void* d_out, int out_size, void* d_ws, size_t ws_size,
                              hipStream_t stream)
{
  const float* x     = (const float*)d_in[0];
  const float* g1    = (const float*)d_in[1];
  const float* b1    = (const float*)d_in[2];
  const float* Wqkv1 = (const float*)d_in[3];
  const float* bqkv1 = (const float*)d_in[4];
  const float* Wout1 = (const float*)d_in[5];
  const float* bout1 = (const float*)d_in[6];
  const float* g2    = (const float*)d_in[7];
  const float* b2    = (const float*)d_in[8];
  const float* Wqkv2 = (const float*)d_in[9];
  const float* bqkv2 = (const float*)d_in[10];
  const float* Wout2 = (const float*)d_in[11];
  const float* bout2 = (const float*)d_in[12];
  const float* gf    = (const float*)d_in[13];
  const float* bfv   = (const float*)d_in[14];
  const float* Wf1   = (const float*)d_in[15];
  const float* bf1   = (const float*)d_in[16];
  const float* Wf2   = (const float*)d_in[17];
  const float* bf2   = (const float*)d_in[18];
  float* out = (float*)d_out;
  char* ws = (char*)d_ws;

  float* stats   = (float*)(ws + 0);          // 64 f (zeroed)
  float* derived = (float*)(ws + 256);        // 64 f
  float* bsum    = (float*)(ws + 512);        // 256 f
  float* Ak1 = (float*)(ws + 1536);
  float* Bk1 = (float*)(ws + 2560);
  float* Av1 = (float*)(ws + 3584);
  float* Bv1 = (float*)(ws + 4608);
  float* Ak2 = (float*)(ws + 5632);
  float* Bk2 = (float*)(ws + 6656);
  float* Av2 = (float*)(ws + 7680);
  float* Bv2 = (float*)(ws + 8704);
  float* A3  = (float*)(ws + 9728);
  float* B3  = (float*)(ws + 11776);
  float* tk1 = (float*)(ws + 13824);
  float* tv1 = (float*)(ws + 30208);
  float* tk2 = (float*)(ws + 46592);
  float* tv2 = (float*)(ws + 62976);
  float* t3  = (float*)(ws + 79360);
  float* Wk1g = (float*)(ws + 112128);
  float* Wk2g = (float*)(ws + 374272);
  u16* Wv1g = (u16*)(ws + 636416);
  u16* Wv2g = (u16*)(ws + 767488);
  u16* Wo1  = (u16*)(ws + 898560);
  u16* Wo2  = (u16*)(ws + 1029632);
  u16* Wf1g = (u16*)(ws + 1160704);
  u16* Wf2b = (u16*)(ws + 1422848);
  float* rawq1   = (float*)(ws + 1684992);
  float* rawq2   = (float*)(ws + 2733568);
  float* scores1 = (float*)(ws + 3782144);
  float* scores2 = (float*)(ws + 4830720);
  float* xs1  = (float*)(ws + 5879296);
  float* xs2  = (float*)(ws + 10073600);
  float* ctx1 = (float*)(ws + 11122176);
  float* ctx2 = (float*)(ws + 15316480);
  // xb: bf16(xnew) in fragment-blob order, 16*16384*256*2 = 128 MiB, at 16 MiB offset
  const size_t XB_OFF  = 16777216;
  const size_t XB_SIZE = (size_t)16*16384*256*2;
  bool fast = (ws_size >= XB_OFF + XB_SIZE);
  u16* xb = fast ? (u16*)(ws + XB_OFF) : (u16*)nullptr;

  hipMemsetAsync(stats, 0, 64*sizeof(float), stream);

  k_prep<<<2304, 256, 0, stream>>>(Wqkv1,g1,b1, Wqkv2,g2,b2, Wout1,Wout2, Wf1,gf,bfv, Wf2, bout1,bout2,
                                   Wk1g,Wk2g, Wv1g,Wv2g,Wo1,Wo2,Wf1g,Wf2b,
                                   Ak1,Bk1,Av1,Bv1, Ak2,Bk2,Av2,Bv2, A3,B3, bsum);
  k_stats_q<<<256, 256, 0, stream>>>(x, Wqkv1,g1, Wqkv2,g2, stats, rawq1, rawq2);
  k_finalize<<<1, 64, 0, stream>>>(stats, derived);
  k_tvec<<<16, 256, 0, stream>>>(derived, bqkv1,bqkv2, Ak1,Bk1,Av1,Bv1, Ak2,Bk2,Av2,Bv2,
                                 tk1,tv1,tk2,tv2);
  k_softmax2<<<1024, 256, 0, stream>>>(rawq2, derived, scores2);
  k_softmax1<<<4096, 64, 0, stream>>>(rawq1, derived, scores1);
  k_xs<<<4096, 256, 0, stream>>>(x, scores1, scores2, xs1, xs2);
  k_ctx2<<<256, 256, 0, stream>>>(Wk2g, xs2, tk2, derived, ctx2);
  k_ctx1<<<1024, 256, 0, stream>>>(Wk1g, xs1, tk1, derived, ctx1);
  k_attn<<<4096, 256, 0, stream>>>(x, Wv1g,Wv2g, Wo1,Wo2, tv1,tv2, ctx1,ctx2,
                                   bsum, derived, out, stats, xb);
  k_finalize3<<<1, 512, 0, stream>>>(stats, derived, bf1, A3, B3, t3);
  if(fast)
    k_ffn3<<<4096, 256, 0, stream>>>(xb, Wf1g, Wf2b, t3, bf2, derived, out);
  else
    k_ffn<<<8192, 256, 0, stream>>>(Wf1g, Wf2b, t3, bf2, derived, out);
}

// Round 4
// 1486.688 us; speedup vs baseline: 1.1387x; 1.0976x over previous
//
#include <hip/hip_runtime.h>

typedef __bf16 bf16x8 __attribute__((ext_vector_type(8)));
typedef float floatx4 __attribute__((ext_vector_type(4)));
typedef unsigned short u16;

#define MFMA16(A,Bv,Cv) __builtin_amdgcn_mfma_f32_16x16x32_bf16(A,Bv,Cv,0,0,0)

__device__ __forceinline__ u16 f2bf(float f){
  unsigned u = __float_as_uint(f);
  return (u16)((u + 0x7fffu + ((u >> 16) & 1u)) >> 16);
}

#define LDK 264   // u16 row stride for [pix][k] LDS tiles (K=256 + 8 pad -> 2-way-free banks)
#define LDO 520   // u16 row stride for K=512 tile

// ---------------- weight prep: fold LN gamma into weights, bf16-convert, row sums ----------------
__global__ void k_prep(const float* __restrict__ Wqkv1, const float* __restrict__ g1, const float* __restrict__ b1,
                       const float* __restrict__ Wqkv2, const float* __restrict__ g2, const float* __restrict__ b2,
                       const float* __restrict__ Wout1, const float* __restrict__ Wout2,
                       const float* __restrict__ Wf1, const float* __restrict__ gf, const float* __restrict__ bfv,
                       const float* __restrict__ Wf2, const float* __restrict__ bout1, const float* __restrict__ bout2,
                       float* __restrict__ Wk1g, float* __restrict__ Wk2g,
                       u16* __restrict__ Wv1g, u16* __restrict__ Wv2g, u16* __restrict__ Wo1, u16* __restrict__ Wo2,
                       u16* __restrict__ Wf1g, u16* __restrict__ Wf2b,
                       float* __restrict__ Ak1, float* __restrict__ Bk1, float* __restrict__ Av1, float* __restrict__ Bv1,
                       float* __restrict__ Ak2, float* __restrict__ Bk2, float* __restrict__ Av2, float* __restrict__ Bv2,
                       float* __restrict__ A3, float* __restrict__ B3, float* __restrict__ bsum)
{
  int bid = blockIdx.x, c = threadIdx.x;
  __shared__ float sa[4], sb[4];
  int wv = c >> 6, ln = c & 63;
  auto rowsum2 = [&](float a, float bb, float* pA, float* pB){
    for(int off=32; off; off>>=1){ a += __shfl_down(a,off,64); bb += __shfl_down(bb,off,64); }
    if(ln==0){ sa[wv]=a; sb[wv]=bb; }
    __syncthreads();
    if(c==0){ *pA = sa[0]+sa[1]+sa[2]+sa[3]; *pB = sb[0]+sb[1]+sb[2]+sb[3]; }
  };
  if(bid < 512){
    int r = bid; float w = Wqkv1[(size_t)(1+r)*256 + c];
    if(r < 256){ float wg = w*g1[c]; Wk1g[(size_t)r*256+c] = wg; rowsum2(wg, w*b1[c], &Ak1[r], &Bk1[r]); }
    else { int rv=r-256; float wg=w*g1[c]; Wv1g[(size_t)rv*256+c] = f2bf(wg); rowsum2(wg, w*b1[c], &Av1[rv], &Bv1[rv]); }
  } else if(bid < 1024){
    int r = bid-512; float w = Wqkv2[(size_t)(1+r)*256 + c];
    if(r < 256){ float wg = w*g2[c]; Wk2g[(size_t)r*256+c] = wg; rowsum2(wg, w*b2[c], &Ak2[r], &Bk2[r]); }
    else { int rv=r-256; float wg=w*g2[c]; Wv2g[(size_t)rv*256+c] = f2bf(wg); rowsum2(wg, w*b2[c], &Av2[rv], &Bv2[rv]); }
  } else if(bid < 1280){
    int r = bid-1024; Wo1[(size_t)r*256+c] = f2bf(Wout1[(size_t)r*256+c]);
    if(bid==1024) bsum[c] = bout1[c] + bout2[c];
  } else if(bid < 1536){
    int r = bid-1280; Wo2[(size_t)r*256+c] = f2bf(Wout2[(size_t)r*256+c]);
  } else if(bid < 2048){
    int r = bid-1536; float w = Wf1[(size_t)r*256+c]; float wg = w*gf[c];
    Wf1g[(size_t)r*256+c] = f2bf(wg); rowsum2(wg, w*bfv[c], &A3[r], &B3[r]);
  } else {
    int r = bid-2048;
    Wf2b[(size_t)r*512+c]     = f2bf(Wf2[(size_t)r*512+c]);
    Wf2b[(size_t)r*512+256+c] = f2bf(Wf2[(size_t)r*512+256+c]);
  }
}

// ---------------- pass 1: per-batch sum/sumsq + raw q for both branches ----------------
__global__ void k_stats_q(const float* __restrict__ x,
                          const float* __restrict__ Wqkv1, const float* __restrict__ g1,
                          const float* __restrict__ Wqkv2, const float* __restrict__ g2,
                          float* __restrict__ stats,
                          float* __restrict__ rawq1, float* __restrict__ rawq2)
{
  int bid = blockIdx.x; int b = bid >> 4, chunk = bid & 15;
  int tid = threadIdx.x;
  __shared__ float wq1[256], wq2[256];
  __shared__ float sred[4], ssred[4];
  wq1[tid] = Wqkv1[tid]*g1[tid];   // row 0 of Wqkv = q projection
  wq2[tid] = Wqkv2[tid]*g2[tid];
  __syncthreads();
  int pix0 = chunk*1024 + tid*4;             // 4 consecutive pixels, same p
  int p = pix0 >> 8, n = pix0 & 255;
  const float* xp = x + ((size_t)b << 22) + pix0;
  float s = 0.f, ss = 0.f;
  floatx4 q1 = {0.f,0.f,0.f,0.f}, q2 = {0.f,0.f,0.f,0.f};
  #pragma unroll 4
  for(int c=0;c<256;c++){
    floatx4 v = *(const floatx4*)&xp[(size_t)c << 14];
    s  += v[0]+v[1]+v[2]+v[3];
    ss += v[0]*v[0]+v[1]*v[1]+v[2]*v[2]+v[3]*v[3];
    q1 += wq1[c]*v;
    q2 += wq2[c]*v;
  }
  *(floatx4*)&rawq2[(size_t)(b*64 + p)*256 + n] = q2;      // [b][p][n]
  #pragma unroll
  for(int i=0;i<4;i++) rawq1[((size_t)(b*256 + n + i))*64 + p] = q1[i];  // [b][n][p]
  int wv = tid>>6, ln = tid&63;
  for(int off=32; off; off>>=1){ s += __shfl_down(s,off,64); ss += __shfl_down(ss,off,64); }
  if(ln==0){ sred[wv]=s; ssred[wv]=ss; }
  __syncthreads();
  if(tid==0){
    atomicAdd(&stats[b],    sred[0]+sred[1]+sred[2]+sred[3]);
    atomicAdd(&stats[16+b], ssred[0]+ssred[1]+ssred[2]+ssred[3]);
  }
}

__global__ void k_finalize(const float* __restrict__ stats, float* __restrict__ derived)
{
  int b = threadIdx.x;
  if(b < 16){
    float M = 4194304.f;
    float mean = stats[b]/M;
    float var  = stats[16+b]/M - mean*mean;
    derived[b] = mean;
    derived[16+b] = rsqrtf(var + 1e-5f);
  }
}

// t[b,o] = bias[o] + sum_c W[o,c]*beta[c] - mean_b*rstd_b*sum_c W[o,c]*g[c]
__global__ void k_tvec(const float* __restrict__ derived,
                       const float* __restrict__ bqkv1, const float* __restrict__ bqkv2,
                       const float* __restrict__ Ak1, const float* __restrict__ Bk1,
                       const float* __restrict__ Av1, const float* __restrict__ Bv1,
                       const float* __restrict__ Ak2, const float* __restrict__ Bk2,
                       const float* __restrict__ Av2, const float* __restrict__ Bv2,
                       float* __restrict__ tk1, float* __restrict__ tv1,
                       float* __restrict__ tk2, float* __restrict__ tv2)
{
  int b = blockIdx.x, c = threadIdx.x;
  float mr = derived[b]*derived[16+b];
  tk1[b*256+c] = bqkv1[1+c]   + Bk1[c] - mr*Ak1[c];
  tv1[b*256+c] = bqkv1[257+c] + Bv1[c] - mr*Av1[c];
  tk2[b*256+c] = bqkv2[1+c]   + Bk2[c] - mr*Ak2[c];
  tv2[b*256+c] = bqkv2[257+c] + Bv2[c] - mr*Av2[c];
}

// softmax over N for rows (b,p)
__global__ void k_softmax2(const float* __restrict__ rawq2, const float* __restrict__ derived,
                           float* __restrict__ scores2)
{
  int row = blockIdx.x; int b = row >> 6; int tid = threadIdx.x;
  __shared__ float sm[4], ssum[4];
  int wv = tid>>6, ln = tid&63;
  float v = derived[16+b]*rawq2[(size_t)row*256 + tid];
  float m = v;
  for(int off=32; off; off>>=1) m = fmaxf(m, __shfl_xor(m,off,64));
  if(ln==0) sm[wv]=m;
  __syncthreads();
  m = fmaxf(fmaxf(sm[0],sm[1]),fmaxf(sm[2],sm[3]));
  float e = __expf(v-m);
  float s = e;
  for(int off=32; off; off>>=1) s += __shfl_xor(s,off,64);
  if(ln==0) ssum[wv]=s;
  __syncthreads();
  s = ssum[0]+ssum[1]+ssum[2]+ssum[3];
  scores2[(size_t)row*256 + tid] = e/s;
}

// softmax over P (64) for rows (b,n) -- one wave
__global__ void k_softmax1(const float* __restrict__ rawq1, const float* __restrict__ derived,
                           float* __restrict__ scores1)
{
  int row = blockIdx.x; int b = row >> 8; int tid = threadIdx.x;
  float v = derived[16+b]*rawq1[(size_t)row*64 + tid];
  float m = v;
  for(int off=32; off; off>>=1) m = fmaxf(m, __shfl_xor(m,off,64));
  float e = __expf(v-m);
  float s = e;
  for(int off=32; off; off>>=1) s += __shfl_xor(s,off,64);
  scores1[(size_t)row*64 + tid] = e/s;
}

// pass 3: xs1[b][c][n] = sum_p S1*x ; xs2[b][c][p] = sum_n S2*x
__global__ void k_xs(const float* __restrict__ x,
                     const float* __restrict__ scores1, const float* __restrict__ scores2,
                     float* __restrict__ xs1, float* __restrict__ xs2)
{
  __shared__ float X[64*257];
  __shared__ float part[256];
  int bid = blockIdx.x; int b = bid >> 8, c = bid & 255;
  int tid = threadIdx.x;
  const float* xp = x + ((size_t)b*4194304 + (size_t)c*16384);
  for(int i=tid; i<16384; i+=256){
    int p = i >> 8, n = i & 255;
    X[p*257 + n] = xp[i];
  }
  __syncthreads();
  {
    int n = tid;
    const float* s1 = scores1 + (size_t)(b*256 + n)*64;
    float acc = 0.f;
    #pragma unroll 8
    for(int p=0;p<64;p++) acc += s1[p]*X[p*257+n];
    xs1[(size_t)(b*256 + c)*256 + n] = acc;
  }
  {
    int p = tid & 63, q = tid >> 6;
    const float* s2 = scores2 + (size_t)(b*64 + p)*256;
    float acc = 0.f;
    #pragma unroll 8
    for(int i=0;i<64;i++){ int n = q*64 + i; acc += s2[n]*X[p*257+n]; }
    part[tid] = acc;
    __syncthreads();
    if(q==0)
      xs2[(size_t)(b*256 + c)*64 + p] = part[p] + part[64+p] + part[128+p] + part[192+p];
  }
}

// ctx2[b][p][o] = rstd*(Wk2g@xs2) + tk2  (store pixel-major so pass5 reads float4 over o)
__global__ void k_ctx2(const float* __restrict__ Wk2g, const float* __restrict__ xs2,
                       const float* __restrict__ tk2, const float* __restrict__ derived,
                       float* __restrict__ ctx2)
{
  __shared__ float xv[4][256];
  int bid = blockIdx.x; int b = bid >> 4, pg = (bid & 15) << 2;
  int o = threadIdx.x;
  #pragma unroll
  for(int j=0;j<4;j++) xv[j][o] = xs2[(size_t)(b*256 + o)*64 + pg + j];
  __syncthreads();
  const float* w = Wk2g + (size_t)o*256;
  float a0=0,a1=0,a2=0,a3=0;
  for(int cc=0;cc<256;cc++){
    float wc = w[cc];
    a0 += wc*xv[0][cc]; a1 += wc*xv[1][cc]; a2 += wc*xv[2][cc]; a3 += wc*xv[3][cc];
  }
  float r = derived[16+b], t = tk2[b*256 + o];
  ctx2[(size_t)(b*64 + pg+0)*256 + o] = r*a0 + t;
  ctx2[(size_t)(b*64 + pg+1)*256 + o] = r*a1 + t;
  ctx2[(size_t)(b*64 + pg+2)*256 + o] = r*a2 + t;
  ctx2[(size_t)(b*64 + pg+3)*256 + o] = r*a3 + t;
}

__global__ void k_ctx1(const float* __restrict__ Wk1g, const float* __restrict__ xs1,
                       const float* __restrict__ tk1, const float* __restrict__ derived,
                       float* __restrict__ ctx1)
{
  __shared__ float xv[4][256];
  int bid = blockIdx.x; int b = bid >> 6, ng = (bid & 63) << 2;
  int o = threadIdx.x;
  #pragma unroll
  for(int j=0;j<4;j++) xv[j][o] = xs1[(size_t)(b*256 + o)*256 + ng + j];
  __syncthreads();
  const float* w = Wk1g + (size_t)o*256;
  float a0=0,a1=0,a2=0,a3=0;
  for(int cc=0;cc<256;cc++){
    float wc = w[cc];
    a0 += wc*xv[0][cc]; a1 += wc*xv[1][cc]; a2 += wc*xv[2][cc]; a3 += wc*xv[3][cc];
  }
  float r = derived[16+b], t = tk1[b*256 + o];
  ctx1[(size_t)(b*256 + ng+0)*256 + o] = r*a0 + t;
  ctx1[(size_t)(b*256 + ng+1)*256 + o] = r*a1 + t;
  ctx1[(size_t)(b*256 + ng+2)*256 + o] = r*a2 + t;
  ctx1[(size_t)(b*256 + ng+3)*256 + o] = r*a3 + t;
}

// ---------------- pass 5: both attention branches fused, MFMA bf16 ----------------
// block = (b, p, 64 n's). v-GEMMs on rstd*x, relu*ctx, Wout GEMMs, +residual -> out (=xnew), LN3 stats.
// Emits xb = bf16(xnew) in MFMA-fragment-blob order:
//   blob g = global_pixel/16 (16 pixels); within blob: [chunk=c/32][lane][8 ch * 2B]
//   -> a wave's B-fragment at k0 is the contiguous 1KB at g*8192 + (k0/32)*1024 + lane*16.
__global__ __launch_bounds__(256,2) void k_attn(
    const float* __restrict__ x,
    const u16* __restrict__ Wv1g, const u16* __restrict__ Wv2g,
    const u16* __restrict__ Wo1, const u16* __restrict__ Wo2,
    const float* __restrict__ tv1, const float* __restrict__ tv2,
    const float* __restrict__ ctx1, const float* __restrict__ ctx2,
    const float* __restrict__ bsum, const float* __restrict__ derived,
    float* __restrict__ out, float* __restrict__ stats,
    u16* __restrict__ xb)
{
  __shared__ u16 Xs[64*LDK];
  __shared__ u16 Os[64*LDK];
  __shared__ float rs[4], rss[4];
  int bid = blockIdx.x;
  int b = bid >> 8, p = (bid >> 2) & 63, n0 = (bid & 3) << 6;
  int tid = threadIdx.x, wv = tid >> 6, lane = tid & 63, lr = lane & 15, lq = lane >> 4;
  float rstd = derived[16+b];

  { // stage X' = bf16(rstd*x) as [pix][k]
    int pix = tid & 63, c0 = (tid >> 6) * 2;
    const float* xp = x + ((size_t)b*4194304 + (size_t)p*256 + n0 + pix);
    for(int cc = c0; cc < 256; cc += 8){
      float v0 = xp[(size_t)cc*16384];
      float v1 = xp[(size_t)(cc+1)*16384];
      unsigned pk = (unsigned)f2bf(rstd*v0) | ((unsigned)f2bf(rstd*v1) << 16);
      *(unsigned*)&Xs[pix*LDK + cc] = pk;
    }
  }
  __syncthreads();

  floatx4 Dv[4][4], Dy[4][4];
  #pragma unroll
  for(int i=0;i<4;i++){
    #pragma unroll
    for(int j=0;j<4;j++) Dy[i][j] = floatx4{0.f,0.f,0.f,0.f};
  }

  auto gemmX = [&](const u16* __restrict__ W){   // Dv = W @ Xs
    #pragma unroll
    for(int i=0;i<4;i++){
      #pragma unroll
      for(int j=0;j<4;j++) Dv[i][j] = floatx4{0.f,0.f,0.f,0.f};
    }
    for(int k0=0;k0<256;k0+=32){
      bf16x8 Bf[4];
      #pragma unroll
      for(int pt=0;pt<4;pt++) Bf[pt] = *(const bf16x8*)&Xs[(pt*16+lr)*LDK + k0 + lq*8];
      #pragma unroll
      for(int ct=0;ct<4;ct++){
        bf16x8 Af = *(const bf16x8*)&W[(size_t)(wv*64+ct*16+lr)*256 + k0 + lq*8];
        #pragma unroll
        for(int pt=0;pt<4;pt++) Dv[ct][pt] = MFMA16(Af, Bf[pt], Dv[ct][pt]);
      }
    }
  };
  auto gemmO = [&](const u16* __restrict__ W){   // Dy += W @ Os
    for(int k0=0;k0<256;k0+=32){
      bf16x8 Bf[4];
      #pragma unroll
      for(int pt=0;pt<4;pt++) Bf[pt] = *(const bf16x8*)&Os[(pt*16+lr)*LDK + k0 + lq*8];
      #pragma unroll
      for(int ct=0;ct<4;ct++){
        bf16x8 Af = *(const bf16x8*)&W[(size_t)(wv*64+ct*16+lr)*256 + k0 + lq*8];
        #pragma unroll
        for(int pt=0;pt<4;pt++) Dy[ct][pt] = MFMA16(Af, Bf[pt], Dy[ct][pt]);
      }
    }
  };

  // ---- branch 2 (no transpose; ctx indexed by (b,c,p)) ----
  gemmX(Wv2g);
  {
    const float* c2row = ctx2 + (size_t)(b*64+p)*256;
    #pragma unroll
    for(int ct=0;ct<4;ct++){
      int cbase = wv*64 + ct*16 + lq*4;
      float4 tvv = *(const float4*)&tv2[b*256 + cbase];
      float4 cx  = *(const float4*)&c2row[cbase];
      float tb[4] = {tvv.x,tvv.y,tvv.z,tvv.w};
      float cb[4] = {cx.x,cx.y,cx.z,cx.w};
      #pragma unroll
      for(int pt=0;pt<4;pt++){
        int pix = pt*16 + lr;
        unsigned lo = (unsigned)f2bf(fmaxf(Dv[ct][pt][0]+tb[0],0.f)*cb[0])
                    | ((unsigned)f2bf(fmaxf(Dv[ct][pt][1]+tb[1],0.f)*cb[1]) << 16);
        unsigned hi = (unsigned)f2bf(fmaxf(Dv[ct][pt][2]+tb[2],0.f)*cb[2])
                    | ((unsigned)f2bf(fmaxf(Dv[ct][pt][3]+tb[3],0.f)*cb[3]) << 16);
        uint2 o4; o4.x=lo; o4.y=hi;
        *(uint2*)&Os[pix*LDK + cbase] = o4;
      }
    }
  }
  __syncthreads();
  gemmO(Wo2);
  __syncthreads();

  // ---- branch 1 (transposed branch; ctx indexed by (b,c,n)) ----
  gemmX(Wv1g);
  {
    #pragma unroll
    for(int ct=0;ct<4;ct++){
      int cbase = wv*64 + ct*16 + lq*4;
      float4 tvv = *(const float4*)&tv1[b*256 + cbase];
      float tb[4] = {tvv.x,tvv.y,tvv.z,tvv.w};
      #pragma unroll
      for(int pt=0;pt<4;pt++){
        int pix = pt*16 + lr;
        int n = n0 + pix;
        float4 cx = *(const float4*)&ctx1[(size_t)(b*256+n)*256 + cbase];
        float cb[4] = {cx.x,cx.y,cx.z,cx.w};
        unsigned lo = (unsigned)f2bf(fmaxf(Dv[ct][pt][0]+tb[0],0.f)*cb[0])
                    | ((unsigned)f2bf(fmaxf(Dv[ct][pt][1]+tb[1],0.f)*cb[1]) << 16);
        unsigned hi = (unsigned)f2bf(fmaxf(Dv[ct][pt][2]+tb[2],0.f)*cb[2])
                    | ((unsigned)f2bf(fmaxf(Dv[ct][pt][3]+tb[3],0.f)*cb[3]) << 16);
        uint2 o4; o4.x=lo; o4.y=hi;
        *(uint2*)&Os[pix*LDK + cbase] = o4;
      }
    }
  }
  __syncthreads();
  gemmO(Wo1);

  // ---- epilogue: xnew = y1 + y2 + bout1+bout2 + x; LN3 stats; emit fragment-blob bf16 copy ----
  float s3=0.f, ss3=0.f;
  #pragma unroll
  for(int ct=0;ct<4;ct++){
    int cbase = wv*64 + ct*16 + lq*4;
    float4 bsv = *(const float4*)&bsum[cbase];
    float bb[4] = {bsv.x,bsv.y,bsv.z,bsv.w};
    #pragma unroll
    for(int pt=0;pt<4;pt++){
      int pix = pt*16 + lr;
      size_t base = (size_t)b*4194304 + (size_t)cbase*16384 + (size_t)p*256 + n0 + pix;
      float vv[4];
      #pragma unroll
      for(int r=0;r<4;r++){
        size_t a = base + (size_t)r*16384;
        float v = Dy[ct][pt][r] + bb[r] + x[a];
        out[a] = v;
        vv[r] = v;
        s3 += v; ss3 += v*v;
      }
      if(xb){
        uint2 pk;
        pk.x = (unsigned)f2bf(vv[0]) | ((unsigned)f2bf(vv[1]) << 16);
        pk.y = (unsigned)f2bf(vv[2]) | ((unsigned)f2bf(vv[3]) << 16);
        // fragment-blob address: blob = b*1024 + p*16 + (n0>>4) + pt ; chunk = cbase>>5
        size_t fo = ((size_t)(b*1024 + p*16 + ((bid&3)<<2) + pt) << 12)
                  + (size_t)(wv*2 + (ct>>1))*512
                  + (size_t)((((ct&1)*2 + (lq>>1))*16 + lr)*8) + (lq&1)*4;
        *(uint2*)&xb[fo] = pk;
      }
    }
  }
  for(int off=32; off; off>>=1){ s3 += __shfl_down(s3,off,64); ss3 += __shfl_down(ss3,off,64); }
  if(lane==0){ rs[wv]=s3; rss[wv]=ss3; }
  __syncthreads();
  if(tid==0){
    atomicAdd(&stats[32+b], rs[0]+rs[1]+rs[2]+rs[3]);
    atomicAdd(&stats[48+b], rss[0]+rss[1]+rss[2]+rss[3]);
  }
}

__global__ void k_finalize3(const float* __restrict__ stats, float* __restrict__ derived,
                            const float* __restrict__ bf1, const float* __restrict__ A3,
                            const float* __restrict__ B3, float* __restrict__ t3)
{
  int tid = threadIdx.x;
  if(tid < 16){
    float M = 4194304.f;
    float mean = stats[32+tid]/M;
    float var  = stats[48+tid]/M - mean*mean;
    derived[32+tid] = mean;
    derived[48+tid] = rsqrtf(var + 1e-5f);
  }
  __syncthreads();
  float a = A3[tid], bb = B3[tid], bias = bf1[tid];
  for(int b=0;b<16;b++){
    float mr = derived[32+b]*derived[48+b];
    t3[b*512 + tid] = bias + bb - mr*a;
  }
}

// ---------------- pass 6 (fast): FFN, 64-pixel tile; latency-hidden float4 epilogue ----------------
// The out RMW epilogue was latency-bound (scalar 4B strided loads at block end -> ~840 GB/s cap).
// Fix: prefetch out as 16 independent float4/thread before GEMM-y (drains under MFMA work);
// LDS-transpose Dy to f32 [ch][68] so the final store is pure float4.
__global__ __launch_bounds__(256,2) void k_ffn4(
    const u16* __restrict__ xb,
    const u16* __restrict__ Wf1g, const u16* __restrict__ Wf2b,
    const float* __restrict__ t3, const float* __restrict__ bf2,
    const float* __restrict__ derived,
    float* __restrict__ out)
{
  __shared__ __align__(16) float Sf[256*68];      // 69632 B; first 64 KB doubles as frag buffer
  u16* S = (u16*)Sf;
  int bid = blockIdx.x;
  int b = bid >> 8, p = (bid >> 2) & 63, n0 = (bid & 3) << 6;
  int tid = threadIdx.x, wv = tid >> 6, lane = tid & 63, lr = lane & 15, lq = lane >> 4;
  float rstd = derived[48+b];

  { // stage 4 contiguous X-frag blobs (32 KB), fully coalesced
    const u16* gsrc = xb + ((size_t)(b*1024 + p*16 + (bid&3)*4) << 12);
    #pragma unroll
    for(int i=0;i<8;i++)
      *(uint4*)&S[i*2048 + tid*8] = *(const uint4*)&gsrc[i*2048 + tid*8];
  }
  __syncthreads();

  // GEMM-h: f = wv*128 + ct*16 (ct=0..7), pix groups pt=0..3 (64 pixels)
  floatx4 Dh[8][4];
  #pragma unroll
  for(int i=0;i<8;i++){
    #pragma unroll
    for(int j=0;j<4;j++) Dh[i][j] = floatx4{0.f,0.f,0.f,0.f};
  }
  for(int k0=0;k0<256;k0+=32){
    bf16x8 Bf[4];
    #pragma unroll
    for(int pt=0;pt<4;pt++) Bf[pt] = *(const bf16x8*)&S[pt*4096 + (k0>>5)*512 + lane*8];
    #pragma unroll
    for(int ct=0;ct<8;ct++){
      bf16x8 Af = *(const bf16x8*)&Wf1g[(size_t)(wv*128+ct*16+lr)*256 + k0 + lq*8];
      #pragma unroll
      for(int pt=0;pt<4;pt++) Dh[ct][pt] = MFMA16(Af, Bf[pt], Dh[ct][pt]);
    }
  }
  __syncthreads();   // all X reads done; S will be overwritten with h frags

  // h = clip(rstd*Dh + t3, -1, 1) -> S in h-frag-blob order [pixblob(4)][kstep(16)][lane][8]
  #pragma unroll
  for(int ct=0;ct<8;ct++){
    int fbase = wv*128 + ct*16 + lq*4;
    float4 tt = *(const float4*)&t3[b*512 + fbase];
    float tb[4] = {tt.x,tt.y,tt.z,tt.w};
    #pragma unroll
    for(int pt=0;pt<4;pt++){
      unsigned lo = (unsigned)f2bf(fminf(fmaxf(rstd*Dh[ct][pt][0]+tb[0],-1.f),1.f))
                  | ((unsigned)f2bf(fminf(fmaxf(rstd*Dh[ct][pt][1]+tb[1],-1.f),1.f)) << 16);
      unsigned hi = (unsigned)f2bf(fminf(fmaxf(rstd*Dh[ct][pt][2]+tb[2],-1.f),1.f))
                  | ((unsigned)f2bf(fminf(fmaxf(rstd*Dh[ct][pt][3]+tb[3],-1.f),1.f)) << 16);
      uint2 o4; o4.x=lo; o4.y=hi;
      int oi = pt*8192 + (wv*4 + (ct>>1))*512 + (((ct&1)*2 + (lq>>1))*16 + lr)*8 + (lq&1)*4;
      *(uint2*)&S[oi] = o4;
    }
  }

  // prefetch out RMW values: thread <-> (channel ch0+16j, 4 consecutive pixels 4q)
  // 16 independent float4 loads; they drain under GEMM-y's MFMA work.
  int q4 = (tid & 15) << 2, ch0 = tid >> 4;
  size_t obase2 = (size_t)b*4194304 + (size_t)p*256 + n0 + q4;
  floatx4 pf[16];
  #pragma unroll
  for(int j=0;j<16;j++)
    pf[j] = *(const floatx4*)&out[obase2 + (size_t)(ch0 + 16*j)*16384];

  __syncthreads();

  // GEMM-y: c = wv*64 + ct*16 (ct=0..3), pix pt=0..3, K=512
  floatx4 Dy[4][4];
  #pragma unroll
  for(int i=0;i<4;i++){
    #pragma unroll
    for(int j=0;j<4;j++) Dy[i][j] = floatx4{0.f,0.f,0.f,0.f};
  }
  for(int k0=0;k0<512;k0+=32){
    bf16x8 Bf[4];
    #pragma unroll
    for(int pt=0;pt<4;pt++) Bf[pt] = *(const bf16x8*)&S[pt*8192 + (k0>>5)*512 + lane*8];
    #pragma unroll
    for(int ct=0;ct<4;ct++){
      bf16x8 Af = *(const bf16x8*)&Wf2b[(size_t)(wv*64+ct*16+lr)*512 + k0 + lq*8];
      #pragma unroll
      for(int pt=0;pt<4;pt++) Dy[ct][pt] = MFMA16(Af, Bf[pt], Dy[ct][pt]);
    }
  }
  __syncthreads();   // h-frag reads done; S reused as f32 transpose tile

  // transpose Dy + bf2 into Sf[ch][68] (scalar writes, conflict-free banks)
  #pragma unroll
  for(int ct=0;ct<4;ct++){
    int obase = wv*64 + ct*16 + lq*4;
    float4 bbv = *(const float4*)&bf2[obase];
    float bb[4] = {bbv.x,bbv.y,bbv.z,bbv.w};
    #pragma unroll
    for(int pt=0;pt<4;pt++){
      int pix = pt*16 + lr;
      #pragma unroll
      for(int r=0;r<4;r++) Sf[(obase+r)*68 + pix] = Dy[ct][pt][r] + bb[r];
    }
  }
  __syncthreads();

  // final: out = prefetched(out) + y + bf2, pure float4 stores
  #pragma unroll
  for(int j=0;j<16;j++){
    int ch = ch0 + 16*j;
    floatx4 v = *(const floatx4*)&Sf[ch*68 + q4];
    floatx4 o = pf[j] + v;
    *(floatx4*)&out[obase2 + (size_t)ch*16384] = o;
  }
}

// ---------------- pass 6 (fallback, if workspace too small for xb): original staging version ----------------
__global__ __launch_bounds__(256,2) void k_ffn(
    const u16* __restrict__ Wf1g, const u16* __restrict__ Wf2b,
    const float* __restrict__ t3, const float* __restrict__ bf2,
    const float* __restrict__ derived,
    float* __restrict__ out)
{
  __shared__ u16 Xs[32*LDK];
  __shared__ u16 Os[32*LDO];
  int bid = blockIdx.x;
  int b = bid >> 9, p = (bid >> 3) & 63, n0 = (bid & 7) << 5;
  int tid = threadIdx.x, wv = tid >> 6, lane = tid & 63, lr = lane & 15, lq = lane >> 4;
  float rstd = derived[48+b];

  { // stage X3' = bf16(rstd3 * xnew)
    int pix = tid & 31, c0 = (tid >> 5) * 2;
    const float* xp = out + ((size_t)b*4194304 + (size_t)p*256 + n0 + pix);
    for(int cc = c0; cc < 256; cc += 16){
      float v0 = xp[(size_t)cc*16384];
      float v1 = xp[(size_t)(cc+1)*16384];
      unsigned pk = (unsigned)f2bf(rstd*v0) | ((unsigned)f2bf(rstd*v1) << 16);
      *(unsigned*)&Xs[pix*LDK + cc] = pk;
    }
  }
  __syncthreads();

  floatx4 Dh[8][2];
  #pragma unroll
  for(int i=0;i<8;i++){ Dh[i][0] = floatx4{0.f,0.f,0.f,0.f}; Dh[i][1] = floatx4{0.f,0.f,0.f,0.f}; }
  for(int k0=0;k0<256;k0+=32){
    bf16x8 Bf[2];
    #pragma unroll
    for(int pt=0;pt<2;pt++) Bf[pt] = *(const bf16x8*)&Xs[(pt*16+lr)*LDK + k0 + lq*8];
    #pragma unroll
    for(int ct=0;ct<8;ct++){
      bf16x8 Af = *(const bf16x8*)&Wf1g[(size_t)(wv*128+ct*16+lr)*256 + k0 + lq*8];
      Dh[ct][0] = MFMA16(Af, Bf[0], Dh[ct][0]);
      Dh[ct][1] = MFMA16(Af, Bf[1], Dh[ct][1]);
    }
  }
  #pragma unroll
  for(int ct=0;ct<8;ct++){
    int fbase = wv*128 + ct*16 + lq*4;
    float4 tt = *(const float4*)&t3[b*512 + fbase];
    float tb[4] = {tt.x,tt.y,tt.z,tt.w};
    #pragma unroll
    for(int pt=0;pt<2;pt++){
      int pix = pt*16 + lr;
      unsigned lo = (unsigned)f2bf(fminf(fmaxf(Dh[ct][pt][0]+tb[0],-1.f),1.f))
                  | ((unsigned)f2bf(fminf(fmaxf(Dh[ct][pt][1]+tb[1],-1.f),1.f)) << 16);
      unsigned hi = (unsigned)f2bf(fminf(fmaxf(Dh[ct][pt][2]+tb[2],-1.f),1.f))
                  | ((unsigned)f2bf(fminf(fmaxf(Dh[ct][pt][3]+tb[3],-1.f),1.f)) << 16);
      uint2 o4; o4.x=lo; o4.y=hi;
      *(uint2*)&Os[pix*LDO + fbase] = o4;
    }
  }
  __syncthreads();

  floatx4 Dy[4][2];
  #pragma unroll
  for(int i=0;i<4;i++){ Dy[i][0] = floatx4{0.f,0.f,0.f,0.f}; Dy[i][1] = floatx4{0.f,0.f,0.f,0.f}; }
  for(int k0=0;k0<512;k0+=32){
    bf16x8 Bf[2];
    #pragma unroll
    for(int pt=0;pt<2;pt++) Bf[pt] = *(const bf16x8*)&Os[(pt*16+lr)*LDO + k0 + lq*8];
    #pragma unroll
    for(int ct=0;ct<4;ct++){
      bf16x8 Af = *(const bf16x8*)&Wf2b[(size_t)(wv*64+ct*16+lr)*512 + k0 + lq*8];
      Dy[ct][0] = MFMA16(Af, Bf[0], Dy[ct][0]);
      Dy[ct][1] = MFMA16(Af, Bf[1], Dy[ct][1]);
    }
  }

  #pragma unroll
  for(int ct=0;ct<4;ct++){
    int obase = wv*64 + ct*16 + lq*4;
    float4 bbv = *(const float4*)&bf2[obase];
    float bb[4] = {bbv.x,bbv.y,bbv.z,bbv.w};
    #pragma unroll
    for(int pt=0;pt<2;pt++){
      int pix = pt*16 + lr;
      size_t base = (size_t)b*4194304 + (size_t)obase*16384 + (size_t)p*256 + n0 + pix;
      #pragma unroll
      for(int r=0;r<4;r++){
        size_t a = base + (size_t)r*16384;
        out[a] = out[a] + Dy[ct][pt][r] + bb[r];
      }
    }
  }
}

// ---------------- launcher ----------------
extern "C" void kernel_launch(void* const* d_in, const int* in_sizes, int n_in,
                              void* d_out, int out_size, void* d_ws, size_t ws_size,
                              hipStream_t stream)
{
  const float* x     = (const float*)d_in[0];
  const float* g1    = (const float*)d_in[1];
  const float* b1    = (const float*)d_in[2];
  const float* Wqkv1 = (const float*)d_in[3];
  const float* bqkv1 = (const float*)d_in[4];
  const float* Wout1 = (const float*)d_in[5];
  const float* bout1 = (const float*)d_in[6];
  const float* g2    = (const float*)d_in[7];
  const float* b2    = (const float*)d_in[8];
  const float* Wqkv2 = (const float*)d_in[9];
  const float* bqkv2 = (const float*)d_in[10];
  const float* Wout2 = (const float*)d_in[11];
  const float* bout2 = (const float*)d_in[12];
  const float* gf    = (const float*)d_in[13];
  const float* bfv   = (const float*)d_in[14];
  const float* Wf1   = (const float*)d_in[15];
  const float* bf1   = (const float*)d_in[16];
  const float* Wf2   = (const float*)d_in[17];
  const float* bf2   = (const float*)d_in[18];
  float* out = (float*)d_out;
  char* ws = (char*)d_ws;

  float* stats   = (float*)(ws + 0);          // 64 f (zeroed)
  float* derived = (float*)(ws + 256);        // 64 f
  float* bsum    = (float*)(ws + 512);        // 256 f
  float* Ak1 = (float*)(ws + 1536);
  float* Bk1 = (float*)(ws + 2560);
  float* Av1 = (float*)(ws + 3584);
  float* Bv1 = (float*)(ws + 4608);
  float* Ak2 = (float*)(ws + 5632);
  float* Bk2 = (float*)(ws + 6656);
  float* Av2 = (float*)(ws + 7680);
  float* Bv2 = (float*)(ws + 8704);
  float* A3  = (float*)(ws + 9728);
  float* B3  = (float*)(ws + 11776);
  float* tk1 = (float*)(ws + 13824);
  float* tv1 = (float*)(ws + 30208);
  float* tk2 = (float*)(ws + 46592);
  float* tv2 = (float*)(ws + 62976);
  float* t3  = (float*)(ws + 79360);
  float* Wk1g = (float*)(ws + 112128);
  float* Wk2g = (float*)(ws + 374272);
  u16* Wv1g = (u16*)(ws + 636416);
  u16* Wv2g = (u16*)(ws + 767488);
  u16* Wo1  = (u16*)(ws + 898560);
  u16* Wo2  = (u16*)(ws + 1029632);
  u16* Wf1g = (u16*)(ws + 1160704);
  u16* Wf2b = (u16*)(ws + 1422848);
  float* rawq1   = (float*)(ws + 1684992);
  float* rawq2   = (float*)(ws + 2733568);
  float* scores1 = (float*)(ws + 3782144);
  float* scores2 = (float*)(ws + 4830720);
  float* xs1  = (float*)(ws + 5879296);
  float* xs2  = (float*)(ws + 10073600);
  float* ctx1 = (float*)(ws + 11122176);
  float* ctx2 = (float*)(ws + 15316480);
  // xb: bf16(xnew) in fragment-blob order, 16*16384*256*2 = 128 MiB, at 16 MiB offset
  const size_t XB_OFF  = 16777216;
  const size_t XB_SIZE = (size_t)16*16384*256*2;
  bool fast = (ws_size >= XB_OFF + XB_SIZE);
  u16* xb = fast ? (u16*)(ws + XB_OFF) : (u16*)nullptr;

  hipMemsetAsync(stats, 0, 64*sizeof(float), stream);

  k_prep<<<2304, 256, 0, stream>>>(Wqkv1,g1,b1, Wqkv2,g2,b2, Wout1,Wout2, Wf1,gf,bfv, Wf2, bout1,bout2,
                                   Wk1g,Wk2g, Wv1g,Wv2g,Wo1,Wo2,Wf1g,Wf2b,
                                   Ak1,Bk1,Av1,Bv1, Ak2,Bk2,Av2,Bv2, A3,B3, bsum);
  k_stats_q<<<256, 256, 0, stream>>>(x, Wqkv1,g1, Wqkv2,g2, stats, rawq1, rawq2);
  k_finalize<<<1, 64, 0, stream>>>(stats, derived);
  k_tvec<<<16, 256, 0, stream>>>(derived, bqkv1,bqkv2, Ak1,Bk1,Av1,Bv1, Ak2,Bk2,Av2,Bv2,
                                 tk1,tv1,tk2,tv2);
  k_softmax2<<<1024, 256, 0, stream>>>(rawq2, derived, scores2);
  k_softmax1<<<4096, 64, 0, stream>>>(rawq1, derived, scores1);
  k_xs<<<4096, 256, 0, stream>>>(x, scores1, scores2, xs1, xs2);
  k_ctx2<<<256, 256, 0, stream>>>(Wk2g, xs2, tk2, derived, ctx2);
  k_ctx1<<<1024, 256, 0, stream>>>(Wk1g, xs1, tk1, derived, ctx1);
  k_attn<<<4096, 256, 0, stream>>>(x, Wv1g,Wv2g, Wo1,Wo2, tv1,tv2, ctx1,ctx2,
                                   bsum, derived, out, stats, xb);
  k_finalize3<<<1, 512, 0, stream>>>(stats, derived, bf1, A3, B3, t3);
  if(fast)
    k_ffn4<<<4096, 256, 0, stream>>>(xb, Wf1g, Wf2b, t3, bf2, derived, out);
  else
    k_ffn<<<8192, 256, 0, stream>>>(Wf1g, Wf2b, t3, bf2, derived, out);
}